// Round 1
// baseline (2051.507 us; speedup 1.0000x reference)
//
#include <hip/hip_runtime.h>
#include <math.h>

#define EPSF 1e-5f

// ---------------- float atomic min/max via int/uint punning ----------------
// Works for mixed signs: non-negative floats compare correctly as ints,
// negative floats compare reversed as uints; int-bits(neg) < int-bits(nonneg).
__device__ inline void atomicMaxF(float* addr, float val) {
    if (val >= 0.f) atomicMax((int*)addr, __float_as_int(val));
    else            atomicMin((unsigned int*)addr, __float_as_uint(val));
}
__device__ inline void atomicMinF(float* addr, float val) {
    if (val >= 0.f) atomicMin((int*)addr, __float_as_int(val));
    else            atomicMax((unsigned int*)addr, __float_as_uint(val));
}

__device__ inline void atomicAddF(float* addr, float val) {
    __hip_atomic_fetch_add(addr, val, __ATOMIC_RELAXED, __HIP_MEMORY_SCOPE_AGENT);
}

// ---------------- init accumulators (ws is re-poisoned each launch) --------
__global__ void init_acc(float* acc_sum, float* acc_sumsq, float* acc_min,
                         float* acc_max, int* deg, int Nd) {
    int i = blockIdx.x * 256 + threadIdx.x;
    int total = Nd * 32;
    if (i < total) {
        acc_sum[i]   = 0.f;
        acc_sumsq[i] = 0.f;
        ((int*)acc_min)[i] = 0x7f800000;           // +inf
        ((int*)acc_max)[i] = (int)0xff800000;      // -inf
    }
    if (i < Nd) deg[i] = 0;
}

// ---------------- edge scatter: 16 threads per edge (one per d) ------------
__global__ __launch_bounds__(256) void edge_scatter(
    const int* __restrict__ src_ids, const int* __restrict__ dst_ids,
    const int* __restrict__ Cat_src, const float* __restrict__ w,
    float* acc_sum, float* acc_sumsq, float* acc_min, float* acc_max,
    int* deg, int E)
{
    long long gid = (long long)blockIdx.x * 256 + threadIdx.x;
    int e = (int)(gid >> 4);
    int d = (int)(gid & 15);
    if (e >= E) return;
    int s = src_ids[e];
    int t = dst_ids[e];
    // recompute h_src on the fly: mean/max over the 4 gathered embedding rows
    float vsum = 0.f, vmax = -INFINITY;
#pragma unroll
    for (int f = 0; f < 4; ++f) {
        int id = Cat_src[s * 4 + f];
        float val = w[id * 16 + d];        // coalesced 64B across the 16 lanes
        vsum += val;
        vmax = fmaxf(vmax, val);
    }
    float vmean = vsum * 0.25f;
    int base0 = (t * 2 + 0) * 16 + d;      // k=0 (mean mode)
    int base1 = base0 + 16;                // k=1 (max mode)
    atomicAddF(&acc_sum[base0], vmean);
    atomicAddF(&acc_sumsq[base0], vmean * vmean);
    atomicMinF(&acc_min[base0], vmean);
    atomicMaxF(&acc_max[base0], vmean);
    atomicAddF(&acc_sum[base1], vmax);
    atomicAddF(&acc_sumsq[base1], vmax * vmax);
    atomicMinF(&acc_min[base1], vmax);
    atomicMaxF(&acc_max[base1], vmax);
    if (d == 0) atomicAdd(&deg[t], 1);
}

// ---------------- finalize: 16 threads per dst node, 16 nodes per block ----
__global__ __launch_bounds__(256) void finalize_kernel(
    const int* __restrict__ Cat_dst, const int* __restrict__ label,
    const float* __restrict__ w,
    const float* __restrict__ W_agg, const float* __restrict__ b_agg,
    const float* __restrict__ w_lin, const float* __restrict__ b_lin,
    const float* __restrict__ W1, const float* __restrict__ b1,
    const float* __restrict__ W2, const float* __restrict__ b2,
    const float* __restrict__ W3, const float* __restrict__ b3,
    const float* __restrict__ acc_sum, const float* __restrict__ acc_sumsq,
    const float* __restrict__ acc_min, const float* __restrict__ acc_max,
    const int* __restrict__ deg_arr,
    float* __restrict__ out, int Nd)
{
    __shared__ float sWagg[2 * 192 * 16];   // 6144
    __shared__ float sW1[96 * 64];          // 6144
    __shared__ float sW2[64 * 32];          // 2048
    __shared__ float sW3[32];
    // pads chosen so row strides are != 0 (mod 32) to break 4-way group conflicts
    __shared__ float s_tmp[16][132];        // idx = k*64 + stat*16 + d
    __shared__ float s_x[16][100];          // idx = f*16 + d
    __shared__ float s_h1[16][68];
    __shared__ float s_h2[16][36];

    int tid = threadIdx.x;
    for (int i = tid; i < 6144; i += 256) sWagg[i] = W_agg[i];
    for (int i = tid; i < 6144; i += 256) sW1[i]   = W1[i];
    for (int i = tid; i < 2048; i += 256) sW2[i]   = W2[i];
    if (tid < 32) sW3[tid] = W3[tid];
    __syncthreads();

    int ln = tid >> 4;          // local node 0..15
    int d  = tid & 15;          // feature lane 0..15
    int n  = blockIdx.x * 16 + ln;
    bool active = n < Nd;

    float amp = 0.f, att = 0.f;
    const float logavg = logf(33.0f);       // log(AVG_D + 1)
    int deg = 0;
    if (active) {
        deg = deg_arr[n];
        float fdeg = (float)deg;
        float safe = fmaxf(fdeg, 1.f);
        float logd = logf(fdeg + 1.f);
        amp = logd / logavg;
        att = (logd > 0.f) ? (logavg / fmaxf(logd, EPSF)) : 0.f;
#pragma unroll
        for (int k = 0; k < 2; ++k) {
            int idx = (n * 2 + k) * 16 + d;
            float mean  = acc_sum[idx] / safe;
            float mean2 = acc_sumsq[idx] / safe;
            float mn = (deg > 0) ? acc_min[idx] : 0.f;
            float mx = (deg > 0) ? acc_max[idx] : 0.f;
            float sd = sqrtf(fmaxf(mean2 - mean * mean, 0.f) + EPSF);
            s_tmp[ln][k * 64 + 0 * 16 + d] = mean;
            s_tmp[ln][k * 64 + 1 * 16 + d] = mn;
            s_tmp[ln][k * 64 + 2 * 16 + d] = mx;
            s_tmp[ln][k * 64 + 3 * 16 + d] = sd;
        }
    }
    __syncthreads();

    float xr[6];
    if (active) {
        // mes[k][d] = sum_f scaled[k][f] * W_agg[k][f][d] + b_agg[k][d]
        // scaled layout: f = block*64 + j, scaler(block) in {1, amp, att}
#pragma unroll
        for (int k = 0; k < 2; ++k) {
            float acc = b_agg[k * 16 + d];
            const float* Wk = &sWagg[k * 192 * 16];
            for (int j = 0; j < 64; ++j) {
                float t0 = s_tmp[ln][k * 64 + j];       // broadcast within group
                const float* col = &Wk[j * 16 + d];
                acc += t0        * col[0];
                acc += (t0 * amp) * col[64 * 16];
                acc += (t0 * att) * col[128 * 16];
            }
            xr[4 + k] = acc;
        }
#pragma unroll
        for (int f = 0; f < 4; ++f) {
            int cid = Cat_dst[n * 4 + f];
            xr[f] = w[cid * 16 + d];
        }
#pragma unroll
        for (int f = 0; f < 6; ++f) s_x[ln][f * 16 + d] = xr[f];
    }
    __syncthreads();

    // linear + FM partials (per-d), reduced over the 16-lane group
    float part = 0.f;
    if (active) {
        float lin = 0.f, s = 0.f, sq = 0.f;
#pragma unroll
        for (int f = 0; f < 6; ++f) {
            lin += xr[f] * w_lin[f * 16 + d];
            s   += xr[f];
            sq  += xr[f] * xr[f];
        }
        part = lin + 0.5f * (s * s - sq);
    }
#pragma unroll
    for (int off = 8; off >= 1; off >>= 1) part += __shfl_xor(part, off);

    // MLP layer 1: each thread computes 4 of the 64 outputs
    if (active) {
#pragma unroll
        for (int jj = 0; jj < 4; ++jj) {
            int j = jj * 16 + d;
            float acc = b1[j];
            for (int i = 0; i < 96; ++i)
                acc += s_x[ln][i] * sW1[i * 64 + j];
            s_h1[ln][j] = fmaxf(acc, 0.f);
        }
    }
    __syncthreads();

    // MLP layer 2: each thread computes 2 of the 32 outputs
    if (active) {
#pragma unroll
        for (int jj = 0; jj < 2; ++jj) {
            int j = jj * 16 + d;
            float acc = b2[j];
            for (int i = 0; i < 64; ++i)
                acc += s_h1[ln][i] * sW2[i * 32 + j];
            s_h2[ln][j] = fmaxf(acc, 0.f);
        }
    }
    __syncthreads();

    // deep output: dot(h2, W3), reduced over group
    float dp = 0.f;
    if (active) dp = s_h2[ln][d] * sW3[d] + s_h2[ln][d + 16] * sW3[d + 16];
#pragma unroll
    for (int off = 8; off >= 1; off >>= 1) dp += __shfl_xor(dp, off);

    if (active && d == 0) {
        float z = part + dp + b_lin[0] + b3[0];
        float pred = 1.f / (1.f + expf(-z));
        out[n]      = pred;
        out[Nd + n] = (float)label[n];
    }
}

extern "C" void kernel_launch(void* const* d_in, const int* in_sizes, int n_in,
                              void* d_out, int out_size, void* d_ws, size_t ws_size,
                              hipStream_t stream) {
    const int*   Cat_src = (const int*)d_in[0];
    const int*   Cat_dst = (const int*)d_in[1];
    const int*   src_ids = (const int*)d_in[2];
    const int*   dst_ids = (const int*)d_in[3];
    const int*   label   = (const int*)d_in[4];
    const float* w       = (const float*)d_in[5];
    const float* W_agg   = (const float*)d_in[6];
    const float* b_agg   = (const float*)d_in[7];
    const float* w_lin   = (const float*)d_in[8];
    const float* b_lin   = (const float*)d_in[9];
    const float* W1      = (const float*)d_in[10];
    const float* b1      = (const float*)d_in[11];
    const float* W2      = (const float*)d_in[12];
    const float* b2      = (const float*)d_in[13];
    const float* W3      = (const float*)d_in[14];
    const float* b3      = (const float*)d_in[15];

    int E  = in_sizes[2];
    int Nd = in_sizes[4];

    // workspace layout (floats): sum | sumsq | min | max | deg(int)
    float* acc_sum   = (float*)d_ws;
    float* acc_sumsq = acc_sum   + (size_t)Nd * 32;
    float* acc_min   = acc_sumsq + (size_t)Nd * 32;
    float* acc_max   = acc_min   + (size_t)Nd * 32;
    int*   deg       = (int*)(acc_max + (size_t)Nd * 32);

    float* out = (float*)d_out;

    {
        int total = Nd * 32;
        int blocks = (total + 255) / 256;
        hipLaunchKernelGGL(init_acc, dim3(blocks), dim3(256), 0, stream,
                           acc_sum, acc_sumsq, acc_min, acc_max, deg, Nd);
    }
    {
        long long totalT = (long long)E * 16;
        int blocks = (int)((totalT + 255) / 256);
        hipLaunchKernelGGL(edge_scatter, dim3(blocks), dim3(256), 0, stream,
                           src_ids, dst_ids, Cat_src, w,
                           acc_sum, acc_sumsq, acc_min, acc_max, deg, E);
    }
    {
        int blocks = (Nd + 15) / 16;
        hipLaunchKernelGGL(finalize_kernel, dim3(blocks), dim3(256), 0, stream,
                           Cat_dst, label, w, W_agg, b_agg, w_lin, b_lin,
                           W1, b1, W2, b2, W3, b3,
                           acc_sum, acc_sumsq, acc_min, acc_max, deg, out, Nd);
    }
}

// Round 2
// 1378.983 us; speedup vs baseline: 1.4877x; 1.4877x over previous
//
#include <hip/hip_runtime.h>
#include <math.h>

#define EPSF 1e-5f
#define CHUNK 1024

// ---------------- zero degree counters ----------------
__global__ void zero_deg(int* deg, int Nd) {
    int i = blockIdx.x * 256 + threadIdx.x;
    if (i < Nd) deg[i] = 0;
}

// ---------------- count degree ----------------
__global__ void count_deg(const int* __restrict__ dst_ids, int* deg, int E) {
    int e = blockIdx.x * 256 + threadIdx.x;
    if (e < E) atomicAdd(&deg[dst_ids[e]], 1);
}

// ---------------- scan phase 1: per-chunk exclusive scan + chunk totals ----
__global__ __launch_bounds__(256) void scan_chunks(const int* __restrict__ deg,
                                                   int* row_start, int* partials, int Nd) {
    __shared__ int lsum[256];
    int bid = blockIdx.x, tid = threadIdx.x;
    int base = bid * CHUNK + tid * 4;
    int v[4];
    int s = 0;
#pragma unroll
    for (int j = 0; j < 4; ++j) {
        int idx = base + j;
        v[j] = (idx < Nd) ? deg[idx] : 0;
        s += v[j];
    }
    lsum[tid] = s;
    __syncthreads();
    for (int off = 1; off < 256; off <<= 1) {
        int y = (tid >= off) ? lsum[tid - off] : 0;
        __syncthreads();
        lsum[tid] += y;
        __syncthreads();
    }
    int excl = lsum[tid] - s;    // exclusive prefix of this thread within chunk
    int run = excl;
#pragma unroll
    for (int j = 0; j < 4; ++j) {
        int idx = base + j;
        if (idx < Nd) row_start[idx] = run;
        run += v[j];
    }
    if (tid == 0) partials[bid] = lsum[255];
}

// ---------------- scan phase 2: serial exclusive scan of chunk totals ------
__global__ void scan_partials(int* partials, int nchunks) {
    if (blockIdx.x == 0 && threadIdx.x == 0) {
        int run = 0;
        for (int i = 0; i < nchunks; ++i) {
            int t = partials[i];
            partials[i] = run;
            run += t;
        }
    }
}

// ---------------- scan phase 3: add chunk offsets; init cursors ------------
__global__ void add_offsets(int* row_start, int* cursor,
                            const int* __restrict__ partials, int Nd) {
    int i = blockIdx.x * 256 + threadIdx.x;
    if (i < Nd) {
        int v = row_start[i] + partials[i / CHUNK];
        row_start[i] = v;
        cursor[i] = v;
    }
}

// ---------------- scatter edges into CSR buckets ----------------
__global__ void scatter_edges(const int* __restrict__ src_ids,
                              const int* __restrict__ dst_ids,
                              int* cursor, int* edge_src, int E) {
    int e = blockIdx.x * 256 + threadIdx.x;
    if (e < E) {
        int t = dst_ids[e];
        int pos = atomicAdd(&cursor[t], 1);
        edge_src[pos] = src_ids[e];
    }
}

// ---------------- fused aggregate + finalize: 16 lanes per dst node --------
__global__ __launch_bounds__(256) void agg_finalize(
    const int* __restrict__ Cat_src, const int* __restrict__ Cat_dst,
    const int* __restrict__ label, const float* __restrict__ w,
    const float* __restrict__ W_agg, const float* __restrict__ b_agg,
    const float* __restrict__ w_lin, const float* __restrict__ b_lin,
    const float* __restrict__ W1, const float* __restrict__ b1,
    const float* __restrict__ W2, const float* __restrict__ b2,
    const float* __restrict__ W3, const float* __restrict__ b3,
    const int* __restrict__ row_start, const int* __restrict__ deg_arr,
    const int* __restrict__ edge_src,
    float* __restrict__ out, int Nd)
{
    __shared__ float sWagg[2 * 192 * 16];   // 24576 B
    __shared__ float sW1[96 * 64];          // 24576 B
    __shared__ float sW2[64 * 32];          // 8192 B
    __shared__ float sW3[32];
    __shared__ float s_tmp[16][132];        // idx = k*64 + stat*16 + d
    __shared__ float s_x[16][100];          // idx = f*16 + d
    __shared__ float s_h1[16][68];
    __shared__ float s_h2[16][36];

    int tid = threadIdx.x;
    for (int i = tid; i < 6144; i += 256) sWagg[i] = W_agg[i];
    for (int i = tid; i < 6144; i += 256) sW1[i]   = W1[i];
    for (int i = tid; i < 2048; i += 256) sW2[i]   = W2[i];
    if (tid < 32) sW3[tid] = W3[tid];
    __syncthreads();

    int ln = tid >> 4;          // local node 0..15
    int d  = tid & 15;          // feature lane 0..15
    int n  = blockIdx.x * 16 + ln;
    bool active = n < Nd;

    // ---- register accumulators for segment stats ----
    float sum0 = 0.f, sq0 = 0.f, mn0 = INFINITY, mx0 = -INFINITY;
    float sum1 = 0.f, sq1 = 0.f, mn1 = INFINITY, mx1 = -INFINITY;
    int deg = 0, rs = 0;
    if (active) { deg = deg_arr[n]; rs = row_start[n]; }

    int i = 0;
    for (; i + 1 < deg; i += 2) {
        int s0e = edge_src[rs + i];
        int s1e = edge_src[rs + i + 1];
        int c0 = Cat_src[s0e * 4 + (d & 3)];
        int c1 = Cat_src[s1e * 4 + (d & 3)];
        float vs0 = 0.f, vm0 = -INFINITY, vs1 = 0.f, vm1 = -INFINITY;
#pragma unroll
        for (int f = 0; f < 4; ++f) {
            int id0 = __shfl(c0, f, 16);
            int id1 = __shfl(c1, f, 16);
            float a = w[id0 * 16 + d];      // one 64B line per group
            float b = w[id1 * 16 + d];
            vs0 += a; vm0 = fmaxf(vm0, a);
            vs1 += b; vm1 = fmaxf(vm1, b);
        }
        float me0 = vs0 * 0.25f, me1 = vs1 * 0.25f;
        sum0 += me0 + me1;
        sq0  += me0 * me0 + me1 * me1;
        mn0 = fminf(mn0, fminf(me0, me1));
        mx0 = fmaxf(mx0, fmaxf(me0, me1));
        sum1 += vm0 + vm1;
        sq1  += vm0 * vm0 + vm1 * vm1;
        mn1 = fminf(mn1, fminf(vm0, vm1));
        mx1 = fmaxf(mx1, fmaxf(vm0, vm1));
    }
    if (i < deg) {
        int s0e = edge_src[rs + i];
        int c0 = Cat_src[s0e * 4 + (d & 3)];
        float vs0 = 0.f, vm0 = -INFINITY;
#pragma unroll
        for (int f = 0; f < 4; ++f) {
            int id0 = __shfl(c0, f, 16);
            float a = w[id0 * 16 + d];
            vs0 += a; vm0 = fmaxf(vm0, a);
        }
        float me0 = vs0 * 0.25f;
        sum0 += me0; sq0 += me0 * me0;
        mn0 = fminf(mn0, me0); mx0 = fmaxf(mx0, me0);
        sum1 += vm0; sq1 += vm0 * vm0;
        mn1 = fminf(mn1, vm0); mx1 = fmaxf(mx1, vm0);
    }

    float amp = 0.f, att = 0.f;
    const float logavg = logf(33.0f);       // log(AVG_D + 1)
    if (active) {
        float fdeg = (float)deg;
        float safe = fmaxf(fdeg, 1.f);
        float logd = logf(fdeg + 1.f);
        amp = logd / logavg;
        att = (logd > 0.f) ? (logavg / fmaxf(logd, EPSF)) : 0.f;
        float rsafe = 1.f / safe;
        float mean0 = sum0 * rsafe, mean1 = sum1 * rsafe;
        float m20 = sq0 * rsafe,    m21 = sq1 * rsafe;
        float sd0 = sqrtf(fmaxf(m20 - mean0 * mean0, 0.f) + EPSF);
        float sd1 = sqrtf(fmaxf(m21 - mean1 * mean1, 0.f) + EPSF);
        bool has = deg > 0;
        s_tmp[ln][0 * 16 + d]       = mean0;
        s_tmp[ln][1 * 16 + d]       = has ? mn0 : 0.f;
        s_tmp[ln][2 * 16 + d]       = has ? mx0 : 0.f;
        s_tmp[ln][3 * 16 + d]       = sd0;
        s_tmp[ln][64 + 0 * 16 + d]  = mean1;
        s_tmp[ln][64 + 1 * 16 + d]  = has ? mn1 : 0.f;
        s_tmp[ln][64 + 2 * 16 + d]  = has ? mx1 : 0.f;
        s_tmp[ln][64 + 3 * 16 + d]  = sd1;
    }
    __syncthreads();

    float xr[6];
    if (active) {
        // mes[k][d] = sum_f scaled[k][f] * W_agg[k][f][d] + b_agg[k][d]
#pragma unroll
        for (int k = 0; k < 2; ++k) {
            float acc = b_agg[k * 16 + d];
            const float* Wk = &sWagg[k * 192 * 16];
            for (int j = 0; j < 64; ++j) {
                float t0 = s_tmp[ln][k * 64 + j];       // group broadcast
                const float* col = &Wk[j * 16 + d];
                acc += t0         * col[0];
                acc += (t0 * amp) * col[64 * 16];
                acc += (t0 * att) * col[128 * 16];
            }
            xr[4 + k] = acc;
        }
#pragma unroll
        for (int f = 0; f < 4; ++f) {
            int cid = Cat_dst[n * 4 + f];
            xr[f] = w[cid * 16 + d];
        }
#pragma unroll
        for (int f = 0; f < 6; ++f) s_x[ln][f * 16 + d] = xr[f];
    }
    __syncthreads();

    // linear + FM partials (per-d), reduced over the 16-lane group
    float part = 0.f;
    if (active) {
        float lin = 0.f, s = 0.f, sq = 0.f;
#pragma unroll
        for (int f = 0; f < 6; ++f) {
            lin += xr[f] * w_lin[f * 16 + d];
            s   += xr[f];
            sq  += xr[f] * xr[f];
        }
        part = lin + 0.5f * (s * s - sq);
    }
#pragma unroll
    for (int off = 8; off >= 1; off >>= 1) part += __shfl_xor(part, off);

    // MLP layer 1: each thread computes 4 of the 64 outputs
    if (active) {
#pragma unroll
        for (int jj = 0; jj < 4; ++jj) {
            int j = jj * 16 + d;
            float acc = b1[j];
            for (int i2 = 0; i2 < 96; ++i2)
                acc += s_x[ln][i2] * sW1[i2 * 64 + j];
            s_h1[ln][j] = fmaxf(acc, 0.f);
        }
    }
    __syncthreads();

    // MLP layer 2: each thread computes 2 of the 32 outputs
    if (active) {
#pragma unroll
        for (int jj = 0; jj < 2; ++jj) {
            int j = jj * 16 + d;
            float acc = b2[j];
            for (int i2 = 0; i2 < 64; ++i2)
                acc += s_h1[ln][i2] * sW2[i2 * 32 + j];
            s_h2[ln][j] = fmaxf(acc, 0.f);
        }
    }
    __syncthreads();

    // deep output: dot(h2, W3), reduced over group
    float dp = 0.f;
    if (active) dp = s_h2[ln][d] * sW3[d] + s_h2[ln][d + 16] * sW3[d + 16];
#pragma unroll
    for (int off = 8; off >= 1; off >>= 1) dp += __shfl_xor(dp, off);

    if (active && d == 0) {
        float z = part + dp + b_lin[0] + b3[0];
        float pred = 1.f / (1.f + expf(-z));
        out[n]      = pred;
        out[Nd + n] = (float)label[n];
    }
}

extern "C" void kernel_launch(void* const* d_in, const int* in_sizes, int n_in,
                              void* d_out, int out_size, void* d_ws, size_t ws_size,
                              hipStream_t stream) {
    const int*   Cat_src = (const int*)d_in[0];
    const int*   Cat_dst = (const int*)d_in[1];
    const int*   src_ids = (const int*)d_in[2];
    const int*   dst_ids = (const int*)d_in[3];
    const int*   label   = (const int*)d_in[4];
    const float* w       = (const float*)d_in[5];
    const float* W_agg   = (const float*)d_in[6];
    const float* b_agg   = (const float*)d_in[7];
    const float* w_lin   = (const float*)d_in[8];
    const float* b_lin   = (const float*)d_in[9];
    const float* W1      = (const float*)d_in[10];
    const float* b1      = (const float*)d_in[11];
    const float* W2      = (const float*)d_in[12];
    const float* b2      = (const float*)d_in[13];
    const float* W3      = (const float*)d_in[14];
    const float* b3      = (const float*)d_in[15];

    int E  = in_sizes[2];
    int Nd = in_sizes[4];
    int nchunks = (Nd + CHUNK - 1) / CHUNK;

    // workspace layout (ints): deg | row_start | cursor | partials(128) | edge_src
    int* deg       = (int*)d_ws;
    int* row_start = deg + Nd;
    int* cursor    = row_start + Nd;
    int* partials  = cursor + Nd;
    int* edge_src  = partials + 128;

    float* out = (float*)d_out;

    int ndBlocks = (Nd + 255) / 256;
    int eBlocks  = (E + 255) / 256;

    hipLaunchKernelGGL(zero_deg, dim3(ndBlocks), dim3(256), 0, stream, deg, Nd);
    hipLaunchKernelGGL(count_deg, dim3(eBlocks), dim3(256), 0, stream, dst_ids, deg, E);
    hipLaunchKernelGGL(scan_chunks, dim3(nchunks), dim3(256), 0, stream,
                       deg, row_start, partials, Nd);
    hipLaunchKernelGGL(scan_partials, dim3(1), dim3(64), 0, stream, partials, nchunks);
    hipLaunchKernelGGL(add_offsets, dim3(ndBlocks), dim3(256), 0, stream,
                       row_start, cursor, partials, Nd);
    hipLaunchKernelGGL(scatter_edges, dim3(eBlocks), dim3(256), 0, stream,
                       src_ids, dst_ids, cursor, edge_src, E);
    hipLaunchKernelGGL(agg_finalize, dim3((Nd + 15) / 16), dim3(256), 0, stream,
                       Cat_src, Cat_dst, label, w, W_agg, b_agg, w_lin, b_lin,
                       W1, b1, W2, b2, W3, b3,
                       row_start, deg, edge_src, out, Nd);
}

// Round 3
// 807.976 us; speedup vs baseline: 2.5391x; 1.7067x over previous
//
#include <hip/hip_runtime.h>
#include <math.h>

#define EPSF 1e-5f
#define CHUNK 1024

// ---------------- zero degree counters ----------------
__global__ void zero_deg(int* deg, int Nd) {
    int i = blockIdx.x * 256 + threadIdx.x;
    if (i < Nd) deg[i] = 0;
}

// ---------------- count degree ----------------
__global__ void count_deg(const int* __restrict__ dst_ids, int* deg, int E) {
    int e = blockIdx.x * 256 + threadIdx.x;
    if (e < E) atomicAdd(&deg[dst_ids[e]], 1);
}

// ---------------- scan phase 1: per-chunk exclusive scan + chunk totals ----
__global__ __launch_bounds__(256) void scan_chunks(const int* __restrict__ deg,
                                                   int* row_start, int* partials, int Nd) {
    __shared__ int lsum[256];
    int bid = blockIdx.x, tid = threadIdx.x;
    int base = bid * CHUNK + tid * 4;
    int v[4];
    int s = 0;
#pragma unroll
    for (int j = 0; j < 4; ++j) {
        int idx = base + j;
        v[j] = (idx < Nd) ? deg[idx] : 0;
        s += v[j];
    }
    lsum[tid] = s;
    __syncthreads();
    for (int off = 1; off < 256; off <<= 1) {
        int y = (tid >= off) ? lsum[tid - off] : 0;
        __syncthreads();
        lsum[tid] += y;
        __syncthreads();
    }
    int run = lsum[tid] - s;
#pragma unroll
    for (int j = 0; j < 4; ++j) {
        int idx = base + j;
        if (idx < Nd) row_start[idx] = run;
        run += v[j];
    }
    if (tid == 0) partials[bid] = lsum[255];
}

// ---------------- scan phase 2: one-block exclusive scan of chunk totals ---
__global__ void scan_partials(int* partials, int nchunks) {
    __shared__ int buf[256];
    int t = threadIdx.x;
    int v = (t < nchunks) ? partials[t] : 0;
    buf[t] = v;
    __syncthreads();
    for (int off = 1; off < 256; off <<= 1) {
        int y = (t >= off) ? buf[t - off] : 0;
        __syncthreads();
        buf[t] += y;
        __syncthreads();
    }
    if (t < nchunks) partials[t] = buf[t] - v;   // exclusive
}

// ---------------- scan phase 3: add chunk offsets; init cursors ------------
__global__ void add_offsets(int* row_start, int* cursor,
                            const int* __restrict__ partials, int Nd) {
    int i = blockIdx.x * 256 + threadIdx.x;
    if (i < Nd) {
        int v = row_start[i] + partials[i / CHUNK];
        row_start[i] = v;
        cursor[i] = v;
    }
}

// ---------------- scatter edges into CSR buckets ----------------
__global__ void scatter_edges(const int* __restrict__ src_ids,
                              const int* __restrict__ dst_ids,
                              int* cursor, int* edge_src, int E) {
    int e = blockIdx.x * 256 + threadIdx.x;
    if (e < E) {
        int t = dst_ids[e];
        int pos = atomicAdd(&cursor[t], 1);
        edge_src[pos] = src_ids[e];
    }
}

// ---------------- aggregate: ONE WAVE per dst node -------------------------
// 4 edges (subgroups) x 16 dims in parallel; batched edge-id + cat loads.
__global__ __launch_bounds__(256) void aggregate(
    const int* __restrict__ Cat_src, const float* __restrict__ w,
    const int* __restrict__ row_start, const int* __restrict__ deg_arr,
    const int* __restrict__ edge_src, float* __restrict__ tmp, int Nd)
{
    int n = (blockIdx.x * 256 + threadIdx.x) >> 6;   // wave-uniform
    if (n >= Nd) return;
    int lane = threadIdx.x & 63;
    int sub = lane >> 4, d = lane & 15;
    int deg = deg_arr[n], rs = row_start[n];

    float sum0 = 0.f, sq0 = 0.f, mn0 = INFINITY, mx0 = -INFINITY;
    float sum1 = 0.f, sq1 = 0.f, mn1 = INFINITY, mx1 = -INFINITY;

    for (int base = 0; base < deg; base += 64) {
        int m = deg - base; if (m > 64) m = 64;
        // one coalesced load covers up to 64 edge ids
        int ei = (base + lane < deg) ? edge_src[rs + base + lane] : 0;
        // cat loads: lane holds field (lane&3) of edge r*16+(lane>>2)
        int cj[4];
#pragma unroll
        for (int r = 0; r < 4; ++r) {
            int sj = __shfl(ei, r * 16 + (lane >> 2), 64);
            cj[r] = Cat_src[sj * 4 + (lane & 3)];
        }
        // 16 iterations of 4 edges each
#pragma unroll 4
        for (int t = 0; t < 16; ++t) {
            int e = t * 4 + sub;
            float vs = 0.f, vm = -INFINITY;
#pragma unroll
            for (int f = 0; f < 4; ++f) {
                int id = __shfl(cj[t >> 2], (t * 4 & 15) * 4 + sub * 4 + f, 64);
                float a = w[id * 16 + d];
                vs += a; vm = fmaxf(vm, a);
            }
            if (e < m) {
                float me = vs * 0.25f;
                sum0 += me; sq0 += me * me;
                mn0 = fminf(mn0, me); mx0 = fmaxf(mx0, me);
                sum1 += vm; sq1 += vm * vm;
                mn1 = fminf(mn1, vm); mx1 = fmaxf(mx1, vm);
            }
        }
    }
    // combine the 4 subgroups (lanes differing in bits 4,5)
#pragma unroll
    for (int off = 16; off <= 32; off <<= 1) {
        sum0 += __shfl_xor(sum0, off); sq0 += __shfl_xor(sq0, off);
        mn0 = fminf(mn0, __shfl_xor(mn0, off)); mx0 = fmaxf(mx0, __shfl_xor(mx0, off));
        sum1 += __shfl_xor(sum1, off); sq1 += __shfl_xor(sq1, off);
        mn1 = fminf(mn1, __shfl_xor(mn1, off)); mx1 = fmaxf(mx1, __shfl_xor(mx1, off));
    }
    float safe = fmaxf((float)deg, 1.f);
    float r = 1.f / safe;
    bool has = deg > 0;
    float mean0 = sum0 * r, mean1 = sum1 * r;
    float sd0 = sqrtf(fmaxf(sq0 * r - mean0 * mean0, 0.f) + EPSF);
    float sd1 = sqrtf(fmaxf(sq1 * r - mean1 * mean1, 0.f) + EPSF);
    float v0 = (sub == 0) ? mean0 : (sub == 1) ? (has ? mn0 : 0.f)
             : (sub == 2) ? (has ? mx0 : 0.f) : sd0;
    float v1 = (sub == 0) ? mean1 : (sub == 1) ? (has ? mn1 : 0.f)
             : (sub == 2) ? (has ? mx1 : 0.f) : sd1;
    float* tp = tmp + (size_t)n * 128;
    tp[lane] = v0;          // k=0: [mean|min|max|std] x 16d == lane
    tp[64 + lane] = v1;     // k=1
}

// ---------------- finalize: ONE NODE per lane, weights via scalar loads ----
__global__ __launch_bounds__(256) void finalize_dense(
    const int* __restrict__ Cat_dst, const int* __restrict__ label,
    const float* __restrict__ w,
    const float* __restrict__ W_agg, const float* __restrict__ b_agg,
    const float* __restrict__ w_lin, const float* __restrict__ b_lin,
    const float* __restrict__ W1, const float* __restrict__ b1,
    const float* __restrict__ W2, const float* __restrict__ b2,
    const float* __restrict__ W3, const float* __restrict__ b3,
    const int* __restrict__ deg_arr, const float* __restrict__ tmp,
    float* __restrict__ out, int Nd)
{
    int n = blockIdx.x * 256 + threadIdx.x;
    if (n >= Nd) return;
    float fdeg = (float)deg_arr[n];
    float logd = logf(fdeg + 1.f);
    const float logavg = logf(33.0f);          // log(AVG_D + 1)
    float amp = logd / logavg;
    float att = (logd > 0.f) ? (logavg / fmaxf(logd, EPSF)) : 0.f;

    // ---- mes[k][d] = scaled @ W_agg + b_agg (weights wave-uniform -> SGPR)
    float mes[32];
    const float4* T4 = (const float4*)(tmp + (size_t)n * 128);
#pragma unroll
    for (int k = 0; k < 2; ++k) {
        float accA[16], accB[16], accC[16];
#pragma unroll
        for (int d = 0; d < 16; ++d) { accA[d] = 0.f; accB[d] = 0.f; accC[d] = 0.f; }
        const float* Wk = W_agg + k * 3072;
        for (int c = 0; c < 16; ++c) {          // rolled: compact body
            float4 t = T4[k * 16 + c];
#pragma unroll
            for (int u = 0; u < 4; ++u) {
                float tv = (u == 0) ? t.x : (u == 1) ? t.y : (u == 2) ? t.z : t.w;
                const float* w0 = Wk + (c * 4 + u) * 16;
#pragma unroll
                for (int d = 0; d < 16; ++d) {
                    accA[d] += tv * w0[d];
                    accB[d] += tv * w0[1024 + d];
                    accC[d] += tv * w0[2048 + d];
                }
            }
        }
#pragma unroll
        for (int d = 0; d < 16; ++d)
            mes[k * 16 + d] = b_agg[k * 16 + d] + accA[d] + amp * accB[d] + att * accC[d];
    }

    // ---- linear + FM (per-d field sums) + W1, streaming x in 16-wide chunks
    float lin = 0.f, sq = 0.f;
    float sd[16];
#pragma unroll
    for (int u = 0; u < 16; ++u) sd[u] = 0.f;
    float acc1[64];
#pragma unroll
    for (int j = 0; j < 64; ++j) acc1[j] = b1[j];

    for (int c = 0; c < 4; ++c) {               // 4 cat-embedding fields
        int cid = Cat_dst[n * 4 + c];
        const float4* R = (const float4*)(w + (size_t)cid * 16);
        float4 r0 = R[0], r1 = R[1], r2 = R[2], r3 = R[3];
        float xi[16] = { r0.x, r0.y, r0.z, r0.w, r1.x, r1.y, r1.z, r1.w,
                         r2.x, r2.y, r2.z, r2.w, r3.x, r3.y, r3.z, r3.w };
#pragma unroll
        for (int u = 0; u < 16; ++u) {
            float v = xi[u];
            int i = c * 16 + u;
            lin += v * w_lin[i];
            sd[u] += v;
            sq += v * v;
#pragma unroll
            for (int j = 0; j < 64; ++j) acc1[j] += v * W1[i * 64 + j];
        }
    }
#pragma unroll
    for (int k = 0; k < 2; ++k) {               // 2 message fields
#pragma unroll
        for (int u = 0; u < 16; ++u) {
            float v = mes[k * 16 + u];
            int i = 64 + k * 16 + u;
            lin += v * w_lin[i];
            sd[u] += v;
            sq += v * v;
#pragma unroll
            for (int j = 0; j < 64; ++j) acc1[j] += v * W1[i * 64 + j];
        }
    }
    float fm = 0.f;
#pragma unroll
    for (int u = 0; u < 16; ++u) fm += sd[u] * sd[u];
    fm = 0.5f * (fm - sq);

    // ---- MLP layers 2,3
    float acc2[32];
#pragma unroll
    for (int j = 0; j < 32; ++j) acc2[j] = b2[j];
#pragma unroll
    for (int i = 0; i < 64; ++i) {
        float h = fmaxf(acc1[i], 0.f);
#pragma unroll
        for (int j = 0; j < 32; ++j) acc2[j] += h * W2[i * 32 + j];
    }
    float deep = b3[0];
#pragma unroll
    for (int j = 0; j < 32; ++j) deep += fmaxf(acc2[j], 0.f) * W3[j];

    float z = lin + b_lin[0] + fm + deep;
    float pred = 1.f / (1.f + expf(-z));
    out[n] = pred;
    out[Nd + n] = (float)label[n];
}

extern "C" void kernel_launch(void* const* d_in, const int* in_sizes, int n_in,
                              void* d_out, int out_size, void* d_ws, size_t ws_size,
                              hipStream_t stream) {
    const int*   Cat_src = (const int*)d_in[0];
    const int*   Cat_dst = (const int*)d_in[1];
    const int*   src_ids = (const int*)d_in[2];
    const int*   dst_ids = (const int*)d_in[3];
    const int*   label   = (const int*)d_in[4];
    const float* w       = (const float*)d_in[5];
    const float* W_agg   = (const float*)d_in[6];
    const float* b_agg   = (const float*)d_in[7];
    const float* w_lin   = (const float*)d_in[8];
    const float* b_lin   = (const float*)d_in[9];
    const float* W1      = (const float*)d_in[10];
    const float* b1      = (const float*)d_in[11];
    const float* W2      = (const float*)d_in[12];
    const float* b2      = (const float*)d_in[13];
    const float* W3      = (const float*)d_in[14];
    const float* b3      = (const float*)d_in[15];

    int E  = in_sizes[2];
    int Nd = in_sizes[4];
    int nchunks = (Nd + CHUNK - 1) / CHUNK;

    // ws layout: deg | row_start | cursor | partials(256) | edge_src(E) | tmp(Nd*128 f32)
    int* deg       = (int*)d_ws;
    int* row_start = deg + Nd;
    int* cursor    = row_start + Nd;
    int* partials  = cursor + Nd;
    int* edge_src  = partials + 256;
    float* tmp     = (float*)(edge_src + E);

    float* out = (float*)d_out;

    int ndBlocks = (Nd + 255) / 256;
    int eBlocks  = (E + 255) / 256;

    hipLaunchKernelGGL(zero_deg, dim3(ndBlocks), dim3(256), 0, stream, deg, Nd);
    hipLaunchKernelGGL(count_deg, dim3(eBlocks), dim3(256), 0, stream, dst_ids, deg, E);
    hipLaunchKernelGGL(scan_chunks, dim3(nchunks), dim3(256), 0, stream,
                       deg, row_start, partials, Nd);
    hipLaunchKernelGGL(scan_partials, dim3(1), dim3(256), 0, stream, partials, nchunks);
    hipLaunchKernelGGL(add_offsets, dim3(ndBlocks), dim3(256), 0, stream,
                       row_start, cursor, partials, Nd);
    hipLaunchKernelGGL(scatter_edges, dim3(eBlocks), dim3(256), 0, stream,
                       src_ids, dst_ids, cursor, edge_src, E);
    hipLaunchKernelGGL(aggregate, dim3((Nd + 3) / 4), dim3(256), 0, stream,
                       Cat_src, w, row_start, deg, edge_src, tmp, Nd);
    hipLaunchKernelGGL(finalize_dense, dim3(ndBlocks), dim3(256), 0, stream,
                       Cat_dst, label, w, W_agg, b_agg, w_lin, b_lin,
                       W1, b1, W2, b2, W3, b3, deg, tmp, out, Nd);
}

// Round 4
// 568.720 us; speedup vs baseline: 3.6072x; 1.4207x over previous
//
#include <hip/hip_runtime.h>
#include <math.h>

#define EPSF 1e-5f
#define MAXB 1024      // max coarse buckets (Nd/128); Nd=100k -> 782
#define BCAP 5120      // per-bucket pair capacity in LDS (avg 4096, 14+ sigma)

// ---------------- zero bucket counters ----------------
__global__ void zero_bcount(int* bcount, int nb) {
    for (int i = threadIdx.x; i < nb; i += 256) bcount[i] = 0;
}

// ---------------- coarse histogram (LDS-privatized) ----------------
__global__ __launch_bounds__(256) void hist_coarse(const int* __restrict__ dst_ids,
                                                   int* bcount, int E, int nb) {
    __shared__ int h[MAXB];
    for (int i = threadIdx.x; i < nb; i += 256) h[i] = 0;
    __syncthreads();
    int stride = gridDim.x * 256;
    for (int e = blockIdx.x * 256 + threadIdx.x; e < E; e += stride)
        atomicAdd(&h[dst_ids[e] >> 7], 1);
    __syncthreads();
    for (int i = threadIdx.x; i < nb; i += 256) {
        int c = h[i];
        if (c) atomicAdd(&bcount[i], c);
    }
}

// ---------------- exclusive scan of bucket counts (single block) -----------
__global__ __launch_bounds__(256) void scan_buckets(const int* __restrict__ bcount,
                                                    int* bstart, int* bcursor, int nb) {
    __shared__ int lsum[256];
    int tid = threadIdx.x;
    int v[4];
    int s = 0;
#pragma unroll
    for (int j = 0; j < 4; ++j) {
        int idx = tid * 4 + j;
        v[j] = (idx < nb) ? bcount[idx] : 0;
        s += v[j];
    }
    lsum[tid] = s;
    __syncthreads();
    for (int off = 1; off < 256; off <<= 1) {
        int y = (tid >= off) ? lsum[tid - off] : 0;
        __syncthreads();
        lsum[tid] += y;
        __syncthreads();
    }
    int run = lsum[tid] - s;
#pragma unroll
    for (int j = 0; j < 4; ++j) {
        int idx = tid * 4 + j;
        if (idx < nb) { bstart[idx] = run; bcursor[idx] = run; }
        run += v[j];
    }
}

// ---------------- scatter packed pairs, tile-ranked for run-writes ---------
// pair = (src << 7) | dst_local   (src < 2^20, dl < 128)
__global__ __launch_bounds__(256) void scatter_pairs(
    const int* __restrict__ src_ids, const int* __restrict__ dst_ids,
    int* bcursor, unsigned* __restrict__ pairs, int E, int nb)
{
    __shared__ int cnt[MAXB];
    __shared__ int base[MAXB];
    int tid = threadIdx.x;
    int t0 = blockIdx.x * 8192;
    for (int i = tid; i < nb; i += 256) cnt[i] = 0;
    __syncthreads();
    int rank[32];
#pragma unroll
    for (int j = 0; j < 32; ++j) {
        int e = t0 + j * 256 + tid;
        rank[j] = (e < E) ? atomicAdd(&cnt[dst_ids[e] >> 7], 1) : 0;
    }
    __syncthreads();
    for (int i = tid; i < nb; i += 256) {
        int c = cnt[i];
        base[i] = c ? atomicAdd(&bcursor[i], c) : 0;
    }
    __syncthreads();
#pragma unroll
    for (int j = 0; j < 32; ++j) {
        int e = t0 + j * 256 + tid;
        if (e < E) {
            int d = dst_ids[e];
            int b = d >> 7;
            pairs[base[b] + rank[j]] = ((unsigned)src_ids[e] << 7) | (unsigned)(d & 127);
        }
    }
}

// ---------------- per-bucket: LDS counting sort by dl + register stats -----
__global__ __launch_bounds__(256) void agg_bucket(
    const int* __restrict__ Cat_src, const float* __restrict__ w,
    const int* __restrict__ bstart, const int* __restrict__ bcount,
    const unsigned* __restrict__ pairs,
    float* __restrict__ tmp, int* __restrict__ deg_out, int Nd)
{
    __shared__ unsigned sp[BCAP];   // dl-sorted pairs
    __shared__ int hist[128];
    __shared__ int ofs[128];
    __shared__ int start[128];

    int b = blockIdx.x;
    int tid = threadIdx.x;
    int cnt = bcount[b];
    int gbase = bstart[b];
    if (cnt > BCAP) cnt = BCAP;     // cannot trigger statistically; guards LDS

    if (tid < 128) hist[tid] = 0;
    __syncthreads();
    for (int i = tid; i < cnt; i += 256)
        atomicAdd(&hist[pairs[gbase + i] & 127u], 1);
    __syncthreads();
    if (tid < 128) ofs[tid] = hist[tid];
    __syncthreads();
    for (int off = 1; off < 128; off <<= 1) {
        int y = (tid < 128 && tid >= off) ? ofs[tid - off] : 0;
        __syncthreads();
        if (tid < 128) ofs[tid] += y;
        __syncthreads();
    }
    if (tid < 128) {
        start[tid] = ofs[tid] - hist[tid];   // exclusive prefix
        ofs[tid] = ofs[tid] - hist[tid];     // cursor
    }
    __syncthreads();
    for (int i = tid; i < cnt; i += 256) {
        unsigned p = pairs[gbase + i];
        int r = atomicAdd(&ofs[p & 127u], 1);
        sp[r] = p;
    }
    __syncthreads();

    int wv = tid >> 6, lane = tid & 63, sub = lane >> 4, d = lane & 15;
#pragma unroll 1
    for (int q = 0; q < 32; ++q) {
        int dl = wv * 32 + q;
        int n = b * 128 + dl;
        if (n >= Nd) break;
        int st = start[dl], dg = hist[dl];
        float sum0 = 0.f, sq0 = 0.f, mn0 = INFINITY, mx0 = -INFINITY;
        float sum1 = 0.f, sq1 = 0.f, mn1 = INFINITY, mx1 = -INFINITY;
        int nt = (dg + 3) >> 2;
        for (int t = 0; t < nt; ++t) {
            int e4 = t * 4 + sub;
            int ec = (e4 < dg) ? e4 : (dg - 1);
            unsigned p = sp[st + ec];
            int src = (int)(p >> 7);
            int cat = Cat_src[src * 4 + (d & 3)];
            float vs = 0.f, vm = -INFINITY;
#pragma unroll
            for (int f = 0; f < 4; ++f) {
                int id = __shfl(cat, sub * 16 + f, 64);
                float a = w[id * 16 + d];
                vs += a; vm = fmaxf(vm, a);
            }
            if (e4 < dg) {
                float me = vs * 0.25f;
                sum0 += me; sq0 += me * me;
                mn0 = fminf(mn0, me); mx0 = fmaxf(mx0, me);
                sum1 += vm; sq1 += vm * vm;
                mn1 = fminf(mn1, vm); mx1 = fmaxf(mx1, vm);
            }
        }
        // reduce across the 4 subgroups (lanes differing in bits 4,5)
#pragma unroll
        for (int off = 16; off <= 32; off <<= 1) {
            sum0 += __shfl_xor(sum0, off); sq0 += __shfl_xor(sq0, off);
            mn0 = fminf(mn0, __shfl_xor(mn0, off)); mx0 = fmaxf(mx0, __shfl_xor(mx0, off));
            sum1 += __shfl_xor(sum1, off); sq1 += __shfl_xor(sq1, off);
            mn1 = fminf(mn1, __shfl_xor(mn1, off)); mx1 = fmaxf(mx1, __shfl_xor(mx1, off));
        }
        float safe = fmaxf((float)dg, 1.f);
        float r = 1.f / safe;
        bool has = dg > 0;
        float mean0 = sum0 * r, mean1 = sum1 * r;
        float sd0 = sqrtf(fmaxf(sq0 * r - mean0 * mean0, 0.f) + EPSF);
        float sd1 = sqrtf(fmaxf(sq1 * r - mean1 * mean1, 0.f) + EPSF);
        float v0 = (sub == 0) ? mean0 : (sub == 1) ? (has ? mn0 : 0.f)
                 : (sub == 2) ? (has ? mx0 : 0.f) : sd0;
        float v1 = (sub == 0) ? mean1 : (sub == 1) ? (has ? mn1 : 0.f)
                 : (sub == 2) ? (has ? mx1 : 0.f) : sd1;
        float* tp = tmp + (size_t)n * 128;
        tp[lane] = v0;
        tp[64 + lane] = v1;
        if (lane == 0) deg_out[n] = dg;
    }
}

// ---------------- finalize: ONE NODE per lane, weights via scalar loads ----
__global__ __launch_bounds__(256) void finalize_dense(
    const int* __restrict__ Cat_dst, const int* __restrict__ label,
    const float* __restrict__ w,
    const float* __restrict__ W_agg, const float* __restrict__ b_agg,
    const float* __restrict__ w_lin, const float* __restrict__ b_lin,
    const float* __restrict__ W1, const float* __restrict__ b1,
    const float* __restrict__ W2, const float* __restrict__ b2,
    const float* __restrict__ W3, const float* __restrict__ b3,
    const int* __restrict__ deg_arr, const float* __restrict__ tmp,
    float* __restrict__ out, int Nd)
{
    int n = blockIdx.x * 256 + threadIdx.x;
    if (n >= Nd) return;
    float fdeg = (float)deg_arr[n];
    float logd = logf(fdeg + 1.f);
    const float logavg = logf(33.0f);          // log(AVG_D + 1)
    float amp = logd / logavg;
    float att = (logd > 0.f) ? (logavg / fmaxf(logd, EPSF)) : 0.f;

    // ---- mes[k][d] = scaled @ W_agg + b_agg (weights wave-uniform -> SGPR)
    float mes[32];
    const float4* T4 = (const float4*)(tmp + (size_t)n * 128);
#pragma unroll
    for (int k = 0; k < 2; ++k) {
        float accA[16], accB[16], accC[16];
#pragma unroll
        for (int d = 0; d < 16; ++d) { accA[d] = 0.f; accB[d] = 0.f; accC[d] = 0.f; }
        const float* Wk = W_agg + k * 3072;
        for (int c = 0; c < 16; ++c) {
            float4 t = T4[k * 16 + c];
#pragma unroll
            for (int u = 0; u < 4; ++u) {
                float tv = (u == 0) ? t.x : (u == 1) ? t.y : (u == 2) ? t.z : t.w;
                const float* w0 = Wk + (c * 4 + u) * 16;
#pragma unroll
                for (int d = 0; d < 16; ++d) {
                    accA[d] += tv * w0[d];
                    accB[d] += tv * w0[1024 + d];
                    accC[d] += tv * w0[2048 + d];
                }
            }
        }
#pragma unroll
        for (int d = 0; d < 16; ++d)
            mes[k * 16 + d] = b_agg[k * 16 + d] + accA[d] + amp * accB[d] + att * accC[d];
    }

    // ---- linear + FM (per-d field sums) + W1, streaming x in 16-wide chunks
    float lin = 0.f, sq = 0.f;
    float sd[16];
#pragma unroll
    for (int u = 0; u < 16; ++u) sd[u] = 0.f;
    float acc1[64];
#pragma unroll
    for (int j = 0; j < 64; ++j) acc1[j] = b1[j];

    for (int c = 0; c < 4; ++c) {
        int cid = Cat_dst[n * 4 + c];
        const float4* R = (const float4*)(w + (size_t)cid * 16);
        float4 r0 = R[0], r1 = R[1], r2 = R[2], r3 = R[3];
        float xi[16] = { r0.x, r0.y, r0.z, r0.w, r1.x, r1.y, r1.z, r1.w,
                         r2.x, r2.y, r2.z, r2.w, r3.x, r3.y, r3.z, r3.w };
#pragma unroll
        for (int u = 0; u < 16; ++u) {
            float v = xi[u];
            int i = c * 16 + u;
            lin += v * w_lin[i];
            sd[u] += v;
            sq += v * v;
#pragma unroll
            for (int j = 0; j < 64; ++j) acc1[j] += v * W1[i * 64 + j];
        }
    }
#pragma unroll
    for (int k = 0; k < 2; ++k) {
#pragma unroll
        for (int u = 0; u < 16; ++u) {
            float v = mes[k * 16 + u];
            int i = 64 + k * 16 + u;
            lin += v * w_lin[i];
            sd[u] += v;
            sq += v * v;
#pragma unroll
            for (int j = 0; j < 64; ++j) acc1[j] += v * W1[i * 64 + j];
        }
    }
    float fm = 0.f;
#pragma unroll
    for (int u = 0; u < 16; ++u) fm += sd[u] * sd[u];
    fm = 0.5f * (fm - sq);

    float acc2[32];
#pragma unroll
    for (int j = 0; j < 32; ++j) acc2[j] = b2[j];
#pragma unroll
    for (int i = 0; i < 64; ++i) {
        float h = fmaxf(acc1[i], 0.f);
#pragma unroll
        for (int j = 0; j < 32; ++j) acc2[j] += h * W2[i * 32 + j];
    }
    float deep = b3[0];
#pragma unroll
    for (int j = 0; j < 32; ++j) deep += fmaxf(acc2[j], 0.f) * W3[j];

    float z = lin + b_lin[0] + fm + deep;
    float pred = 1.f / (1.f + expf(-z));
    out[n] = pred;
    out[Nd + n] = (float)label[n];
}

extern "C" void kernel_launch(void* const* d_in, const int* in_sizes, int n_in,
                              void* d_out, int out_size, void* d_ws, size_t ws_size,
                              hipStream_t stream) {
    const int*   Cat_src = (const int*)d_in[0];
    const int*   Cat_dst = (const int*)d_in[1];
    const int*   src_ids = (const int*)d_in[2];
    const int*   dst_ids = (const int*)d_in[3];
    const int*   label   = (const int*)d_in[4];
    const float* w       = (const float*)d_in[5];
    const float* W_agg   = (const float*)d_in[6];
    const float* b_agg   = (const float*)d_in[7];
    const float* w_lin   = (const float*)d_in[8];
    const float* b_lin   = (const float*)d_in[9];
    const float* W1      = (const float*)d_in[10];
    const float* b1      = (const float*)d_in[11];
    const float* W2      = (const float*)d_in[12];
    const float* b2      = (const float*)d_in[13];
    const float* W3      = (const float*)d_in[14];
    const float* b3      = (const float*)d_in[15];

    int E  = in_sizes[2];
    int Nd = in_sizes[4];
    int nb = (Nd + 127) >> 7;       // 782 coarse buckets of 128 dst

    // ws layout (ints): bcount[MAXB] | bstart[MAXB] | bcursor[MAXB] | deg[Nd]
    //                   | pairs[E] (u32) | tmp[Nd*128] (f32)
    int* bcount  = (int*)d_ws;
    int* bstart  = bcount + MAXB;
    int* bcursor = bstart + MAXB;
    int* deg     = bcursor + MAXB;
    unsigned* pairs = (unsigned*)(deg + Nd);
    float* tmp   = (float*)(pairs + E);

    float* out = (float*)d_out;

    hipLaunchKernelGGL(zero_bcount, dim3(1), dim3(256), 0, stream, bcount, nb);
    hipLaunchKernelGGL(hist_coarse, dim3(512), dim3(256), 0, stream,
                       dst_ids, bcount, E, nb);
    hipLaunchKernelGGL(scan_buckets, dim3(1), dim3(256), 0, stream,
                       bcount, bstart, bcursor, nb);
    hipLaunchKernelGGL(scatter_pairs, dim3((E + 8191) / 8192), dim3(256), 0, stream,
                       src_ids, dst_ids, bcursor, pairs, E, nb);
    hipLaunchKernelGGL(agg_bucket, dim3(nb), dim3(256), 0, stream,
                       Cat_src, w, bstart, bcount, pairs, tmp, deg, Nd);
    hipLaunchKernelGGL(finalize_dense, dim3((Nd + 255) / 256), dim3(256), 0, stream,
                       Cat_dst, label, w, W_agg, b_agg, w_lin, b_lin,
                       W1, b1, W2, b2, W3, b3, deg, tmp, out, Nd);
}

// Round 5
// 515.408 us; speedup vs baseline: 3.9804x; 1.1034x over previous
//
#include <hip/hip_runtime.h>
#include <math.h>

#define EPSF 1e-5f
#define MAXB 1024      // max coarse buckets (Nd/128); Nd=100k -> 782
#define BCAP 5120      // per-bucket pair capacity in LDS (avg 4096, 16 sigma)

__device__ inline unsigned f2bf_rne(float x) {
    unsigned u = __float_as_uint(x);
    u += 0x7FFF + ((u >> 16) & 1);
    return u >> 16;
}
__device__ inline float bf2f_lo(unsigned hv) { return __uint_as_float(hv << 16); }
__device__ inline float bf2f_hi(unsigned hv) { return __uint_as_float(hv & 0xFFFF0000u); }

// ---------------- cast w to bf16 (3.2 MB -> per-XCD L2 resident) -----------
__global__ void cast_w(const float* __restrict__ w, ushort* __restrict__ wb, int n) {
    int i4 = (blockIdx.x * 256 + threadIdx.x) * 4;
    if (i4 + 3 < n) {
        float4 v = *(const float4*)(w + i4);
        ushort4 o;
        o.x = (ushort)f2bf_rne(v.x); o.y = (ushort)f2bf_rne(v.y);
        o.z = (ushort)f2bf_rne(v.z); o.w = (ushort)f2bf_rne(v.w);
        *(ushort4*)(wb + i4) = o;
    } else {
        for (int j = i4; j < n; ++j) wb[j] = (ushort)f2bf_rne(w[j]);
    }
}

// ---------------- precompute h_src: one 64B line per source node -----------
// h[s*16+d] = bf16(mean_f w[cat]) | bf16(max_f w[cat]) << 16
__global__ __launch_bounds__(256) void build_h(
    const int* __restrict__ Cat_src, const ushort* __restrict__ wb,
    unsigned* __restrict__ h, int Ns)
{
    int gid = blockIdx.x * 256 + threadIdx.x;
    int s = gid >> 4;
    if (s >= Ns) return;
    int lane = threadIdx.x & 63;
    int d = lane & 15;
    int c = Cat_src[s * 4 + (d & 3)];
    float vs = 0.f, vm = -INFINITY;
#pragma unroll
    for (int f = 0; f < 4; ++f) {
        int id = __shfl(c, (lane & 48) + f, 64);
        float a = bf2f_lo(wb[id * 16 + d]);
        vs += a; vm = fmaxf(vm, a);
    }
    unsigned packed = f2bf_rne(vs * 0.25f) | (f2bf_rne(vm) << 16);
    __builtin_nontemporal_store(packed, &h[s * 16 + d]);
}

// ---------------- zero bucket counters ----------------
__global__ void zero_bcount(int* bcount, int nb) {
    for (int i = threadIdx.x; i < nb; i += 256) bcount[i] = 0;
}

// ---------------- coarse histogram (LDS-privatized) ----------------
__global__ __launch_bounds__(256) void hist_coarse(const int* __restrict__ dst_ids,
                                                   int* bcount, int E, int nb) {
    __shared__ int h[MAXB];
    for (int i = threadIdx.x; i < nb; i += 256) h[i] = 0;
    __syncthreads();
    int stride = gridDim.x * 256;
    for (int e = blockIdx.x * 256 + threadIdx.x; e < E; e += stride)
        atomicAdd(&h[dst_ids[e] >> 7], 1);
    __syncthreads();
    for (int i = threadIdx.x; i < nb; i += 256) {
        int c = h[i];
        if (c) atomicAdd(&bcount[i], c);
    }
}

// ---------------- exclusive scan of bucket counts (single block) -----------
__global__ __launch_bounds__(256) void scan_buckets(const int* __restrict__ bcount,
                                                    int* bstart, int* bcursor, int nb) {
    __shared__ int lsum[256];
    int tid = threadIdx.x;
    int v[4];
    int s = 0;
#pragma unroll
    for (int j = 0; j < 4; ++j) {
        int idx = tid * 4 + j;
        v[j] = (idx < nb) ? bcount[idx] : 0;
        s += v[j];
    }
    lsum[tid] = s;
    __syncthreads();
    for (int off = 1; off < 256; off <<= 1) {
        int y = (tid >= off) ? lsum[tid - off] : 0;
        __syncthreads();
        lsum[tid] += y;
        __syncthreads();
    }
    int run = lsum[tid] - s;
#pragma unroll
    for (int j = 0; j < 4; ++j) {
        int idx = tid * 4 + j;
        if (idx < nb) { bstart[idx] = run; bcursor[idx] = run; }
        run += v[j];
    }
}

// ---------------- scatter packed pairs, tile-ranked for run-writes ---------
// pair = (src << 7) | dst_local   (src < 2^20, dl < 128)
__global__ __launch_bounds__(256) void scatter_pairs(
    const int* __restrict__ src_ids, const int* __restrict__ dst_ids,
    int* bcursor, unsigned* __restrict__ pairs, int E, int nb)
{
    __shared__ int cnt[MAXB];
    __shared__ int base[MAXB];
    int tid = threadIdx.x;
    int t0 = blockIdx.x * 8192;
    for (int i = tid; i < nb; i += 256) cnt[i] = 0;
    __syncthreads();
    int rank[32];
#pragma unroll
    for (int j = 0; j < 32; ++j) {
        int e = t0 + j * 256 + tid;
        rank[j] = (e < E) ? atomicAdd(&cnt[dst_ids[e] >> 7], 1) : 0;
    }
    __syncthreads();
    for (int i = tid; i < nb; i += 256) {
        int c = cnt[i];
        base[i] = c ? atomicAdd(&bcursor[i], c) : 0;
    }
    __syncthreads();
#pragma unroll
    for (int j = 0; j < 32; ++j) {
        int e = t0 + j * 256 + tid;
        if (e < E) {
            int d = dst_ids[e];
            int b = d >> 7;
            pairs[base[b] + rank[j]] = ((unsigned)src_ids[e] << 7) | (unsigned)(d & 127);
        }
    }
}

// ====== per-bucket aggregation: LDS counting sort + register stats =========
// Shared prologue macro'd by hand: three variants differ only in the gather.

__device__ inline void bucket_sort(const unsigned* __restrict__ pairs,
                                   int gbase, int cnt,
                                   unsigned* sp, int* hist, int* ofs, int* start,
                                   int tid)
{
    if (tid < 128) hist[tid] = 0;
    __syncthreads();
    for (int i = tid; i < cnt; i += 256)
        atomicAdd(&hist[__builtin_nontemporal_load(&pairs[gbase + i]) & 127u], 1);
    __syncthreads();
    if (tid < 128) ofs[tid] = hist[tid];
    __syncthreads();
    for (int off = 1; off < 128; off <<= 1) {
        int y = (tid < 128 && tid >= off) ? ofs[tid - off] : 0;
        __syncthreads();
        if (tid < 128) ofs[tid] += y;
        __syncthreads();
    }
    if (tid < 128) {
        start[tid] = ofs[tid] - hist[tid];
        ofs[tid] = ofs[tid] - hist[tid];
    }
    __syncthreads();
    for (int i = tid; i < cnt; i += 256) {
        unsigned p = __builtin_nontemporal_load(&pairs[gbase + i]);
        int r = atomicAdd(&ofs[p & 127u], 1);
        sp[r] = p;
    }
    __syncthreads();
}

__device__ inline void emit_stats(float sum0, float sq0, float mn0, float mx0,
                                  float sum1, float sq1, float mn1, float mx1,
                                  int dg, int n, int lane, int sub,
                                  float* __restrict__ tmp, int* __restrict__ deg_out)
{
#pragma unroll
    for (int off = 16; off <= 32; off <<= 1) {
        sum0 += __shfl_xor(sum0, off); sq0 += __shfl_xor(sq0, off);
        mn0 = fminf(mn0, __shfl_xor(mn0, off)); mx0 = fmaxf(mx0, __shfl_xor(mx0, off));
        sum1 += __shfl_xor(sum1, off); sq1 += __shfl_xor(sq1, off);
        mn1 = fminf(mn1, __shfl_xor(mn1, off)); mx1 = fmaxf(mx1, __shfl_xor(mx1, off));
    }
    float safe = fmaxf((float)dg, 1.f);
    float r = 1.f / safe;
    bool has = dg > 0;
    float mean0 = sum0 * r, mean1 = sum1 * r;
    float sd0 = sqrtf(fmaxf(sq0 * r - mean0 * mean0, 0.f) + EPSF);
    float sd1 = sqrtf(fmaxf(sq1 * r - mean1 * mean1, 0.f) + EPSF);
    float v0 = (sub == 0) ? mean0 : (sub == 1) ? (has ? mn0 : 0.f)
             : (sub == 2) ? (has ? mx0 : 0.f) : sd0;
    float v1 = (sub == 0) ? mean1 : (sub == 1) ? (has ? mn1 : 0.f)
             : (sub == 2) ? (has ? mx1 : 0.f) : sd1;
    float* tp = tmp + (size_t)n * 128;
    __builtin_nontemporal_store(v0, &tp[lane]);
    __builtin_nontemporal_store(v1, &tp[64 + lane]);
    if (lane == 0) deg_out[n] = dg;
}

// ---- variant: gather from precomputed packed h (one 64B line per edge) ----
__global__ __launch_bounds__(256) void agg_from_h(
    const unsigned* __restrict__ h,
    const int* __restrict__ bstart, const int* __restrict__ bcount,
    const unsigned* __restrict__ pairs,
    float* __restrict__ tmp, int* __restrict__ deg_out, int Nd)
{
    __shared__ unsigned sp[BCAP];
    __shared__ int hist[128];
    __shared__ int ofs[128];
    __shared__ int start[128];
    int b = blockIdx.x, tid = threadIdx.x;
    int cnt = bcount[b];
    int gbase = bstart[b];
    if (cnt > BCAP) cnt = BCAP;
    bucket_sort(pairs, gbase, cnt, sp, hist, ofs, start, tid);

    int wv = tid >> 6, lane = tid & 63, sub = lane >> 4, d = lane & 15;
#pragma unroll 1
    for (int q = 0; q < 32; ++q) {
        int dl = wv * 32 + q;
        int n = b * 128 + dl;
        if (n >= Nd) break;
        int st = start[dl], dg = hist[dl];
        float sum0 = 0.f, sq0 = 0.f, mn0 = INFINITY, mx0 = -INFINITY;
        float sum1 = 0.f, sq1 = 0.f, mn1 = INFINITY, mx1 = -INFINITY;
        int nt = (dg + 3) >> 2;
        for (int t = 0; t < nt; ++t) {
            int e4 = t * 4 + sub;
            int ec = (e4 < dg) ? e4 : (dg - 1);
            unsigned p = sp[st + ec];
            unsigned hv = h[(p >> 7) * 16 + d];     // sub's 16 lanes = 1 line
            float me = bf2f_lo(hv);
            float vm = bf2f_hi(hv);
            if (e4 < dg) {
                sum0 += me; sq0 += me * me;
                mn0 = fminf(mn0, me); mx0 = fmaxf(mx0, me);
                sum1 += vm; sq1 += vm * vm;
                mn1 = fminf(mn1, vm); mx1 = fmaxf(mx1, vm);
            }
        }
        emit_stats(sum0, sq0, mn0, mx0, sum1, sq1, mn1, mx1,
                   dg, n, lane, sub, tmp, deg_out);
    }
}

// ---- variant: gather w per edge (bf16 table if use_bf, else fp32) ---------
__global__ __launch_bounds__(256) void agg_from_w(
    const int* __restrict__ Cat_src, const float* __restrict__ w,
    const ushort* __restrict__ wb, int use_bf,
    const int* __restrict__ bstart, const int* __restrict__ bcount,
    const unsigned* __restrict__ pairs,
    float* __restrict__ tmp, int* __restrict__ deg_out, int Nd)
{
    __shared__ unsigned sp[BCAP];
    __shared__ int hist[128];
    __shared__ int ofs[128];
    __shared__ int start[128];
    int b = blockIdx.x, tid = threadIdx.x;
    int cnt = bcount[b];
    int gbase = bstart[b];
    if (cnt > BCAP) cnt = BCAP;
    bucket_sort(pairs, gbase, cnt, sp, hist, ofs, start, tid);

    int wv = tid >> 6, lane = tid & 63, sub = lane >> 4, d = lane & 15;
#pragma unroll 1
    for (int q = 0; q < 32; ++q) {
        int dl = wv * 32 + q;
        int n = b * 128 + dl;
        if (n >= Nd) break;
        int st = start[dl], dg = hist[dl];
        float sum0 = 0.f, sq0 = 0.f, mn0 = INFINITY, mx0 = -INFINITY;
        float sum1 = 0.f, sq1 = 0.f, mn1 = INFINITY, mx1 = -INFINITY;
        int nt = (dg + 3) >> 2;
        for (int t = 0; t < nt; ++t) {
            int e4 = t * 4 + sub;
            int ec = (e4 < dg) ? e4 : (dg - 1);
            unsigned p = sp[st + ec];
            int src = (int)(p >> 7);
            int cat = Cat_src[src * 4 + (d & 3)];
            float vs = 0.f, vm = -INFINITY;
            if (use_bf) {
#pragma unroll
                for (int f = 0; f < 4; ++f) {
                    int id = __shfl(cat, sub * 16 + f, 64);
                    float a = bf2f_lo(wb[id * 16 + d]);
                    vs += a; vm = fmaxf(vm, a);
                }
            } else {
#pragma unroll
                for (int f = 0; f < 4; ++f) {
                    int id = __shfl(cat, sub * 16 + f, 64);
                    float a = w[id * 16 + d];
                    vs += a; vm = fmaxf(vm, a);
                }
            }
            if (e4 < dg) {
                float me = vs * 0.25f;
                sum0 += me; sq0 += me * me;
                mn0 = fminf(mn0, me); mx0 = fmaxf(mx0, me);
                sum1 += vm; sq1 += vm * vm;
                mn1 = fminf(mn1, vm); mx1 = fmaxf(mx1, vm);
            }
        }
        emit_stats(sum0, sq0, mn0, mx0, sum1, sq1, mn1, mx1,
                   dg, n, lane, sub, tmp, deg_out);
    }
}

// ---------------- finalize: ONE NODE per lane, weights via scalar loads ----
__global__ __launch_bounds__(256) void finalize_dense(
    const int* __restrict__ Cat_dst, const int* __restrict__ label,
    const float* __restrict__ w,
    const float* __restrict__ W_agg, const float* __restrict__ b_agg,
    const float* __restrict__ w_lin, const float* __restrict__ b_lin,
    const float* __restrict__ W1, const float* __restrict__ b1,
    const float* __restrict__ W2, const float* __restrict__ b2,
    const float* __restrict__ W3, const float* __restrict__ b3,
    const int* __restrict__ deg_arr, const float* __restrict__ tmp,
    float* __restrict__ out, int Nd)
{
    int n = blockIdx.x * 256 + threadIdx.x;
    if (n >= Nd) return;
    float fdeg = (float)deg_arr[n];
    float logd = logf(fdeg + 1.f);
    const float logavg = logf(33.0f);          // log(AVG_D + 1)
    float amp = logd / logavg;
    float att = (logd > 0.f) ? (logavg / fmaxf(logd, EPSF)) : 0.f;

    float mes[32];
    const float4* T4 = (const float4*)(tmp + (size_t)n * 128);
#pragma unroll
    for (int k = 0; k < 2; ++k) {
        float accA[16], accB[16], accC[16];
#pragma unroll
        for (int d = 0; d < 16; ++d) { accA[d] = 0.f; accB[d] = 0.f; accC[d] = 0.f; }
        const float* Wk = W_agg + k * 3072;
        for (int c = 0; c < 16; ++c) {
            float4 t = T4[k * 16 + c];
#pragma unroll
            for (int u = 0; u < 4; ++u) {
                float tv = (u == 0) ? t.x : (u == 1) ? t.y : (u == 2) ? t.z : t.w;
                const float* w0 = Wk + (c * 4 + u) * 16;
#pragma unroll
                for (int d = 0; d < 16; ++d) {
                    accA[d] += tv * w0[d];
                    accB[d] += tv * w0[1024 + d];
                    accC[d] += tv * w0[2048 + d];
                }
            }
        }
#pragma unroll
        for (int d = 0; d < 16; ++d)
            mes[k * 16 + d] = b_agg[k * 16 + d] + accA[d] + amp * accB[d] + att * accC[d];
    }

    float lin = 0.f, sq = 0.f;
    float sd[16];
#pragma unroll
    for (int u = 0; u < 16; ++u) sd[u] = 0.f;
    float acc1[64];
#pragma unroll
    for (int j = 0; j < 64; ++j) acc1[j] = b1[j];

    for (int c = 0; c < 4; ++c) {
        int cid = Cat_dst[n * 4 + c];
        const float4* R = (const float4*)(w + (size_t)cid * 16);
        float4 r0 = R[0], r1 = R[1], r2 = R[2], r3 = R[3];
        float xi[16] = { r0.x, r0.y, r0.z, r0.w, r1.x, r1.y, r1.z, r1.w,
                         r2.x, r2.y, r2.z, r2.w, r3.x, r3.y, r3.z, r3.w };
#pragma unroll
        for (int u = 0; u < 16; ++u) {
            float v = xi[u];
            int i = c * 16 + u;
            lin += v * w_lin[i];
            sd[u] += v;
            sq += v * v;
#pragma unroll
            for (int j = 0; j < 64; ++j) acc1[j] += v * W1[i * 64 + j];
        }
    }
#pragma unroll
    for (int k = 0; k < 2; ++k) {
#pragma unroll
        for (int u = 0; u < 16; ++u) {
            float v = mes[k * 16 + u];
            int i = 64 + k * 16 + u;
            lin += v * w_lin[i];
            sd[u] += v;
            sq += v * v;
#pragma unroll
            for (int j = 0; j < 64; ++j) acc1[j] += v * W1[i * 64 + j];
        }
    }
    float fm = 0.f;
#pragma unroll
    for (int u = 0; u < 16; ++u) fm += sd[u] * sd[u];
    fm = 0.5f * (fm - sq);

    float acc2[32];
#pragma unroll
    for (int j = 0; j < 32; ++j) acc2[j] = b2[j];
#pragma unroll
    for (int i = 0; i < 64; ++i) {
        float h = fmaxf(acc1[i], 0.f);
#pragma unroll
        for (int j = 0; j < 32; ++j) acc2[j] += h * W2[i * 32 + j];
    }
    float deep = b3[0];
#pragma unroll
    for (int j = 0; j < 32; ++j) deep += fmaxf(acc2[j], 0.f) * W3[j];

    float z = lin + b_lin[0] + fm + deep;
    float pred = 1.f / (1.f + expf(-z));
    out[n] = pred;
    out[Nd + n] = (float)label[n];
}

extern "C" void kernel_launch(void* const* d_in, const int* in_sizes, int n_in,
                              void* d_out, int out_size, void* d_ws, size_t ws_size,
                              hipStream_t stream) {
    const int*   Cat_src = (const int*)d_in[0];
    const int*   Cat_dst = (const int*)d_in[1];
    const int*   src_ids = (const int*)d_in[2];
    const int*   dst_ids = (const int*)d_in[3];
    const int*   label   = (const int*)d_in[4];
    const float* w       = (const float*)d_in[5];
    const float* W_agg   = (const float*)d_in[6];
    const float* b_agg   = (const float*)d_in[7];
    const float* w_lin   = (const float*)d_in[8];
    const float* b_lin   = (const float*)d_in[9];
    const float* W1      = (const float*)d_in[10];
    const float* b1      = (const float*)d_in[11];
    const float* W2      = (const float*)d_in[12];
    const float* b2      = (const float*)d_in[13];
    const float* W3      = (const float*)d_in[14];
    const float* b3      = (const float*)d_in[15];

    int E  = in_sizes[2];
    int Nd = in_sizes[4];
    int Ns = in_sizes[0] / 4;       // Cat_src is Ns x 4
    int VD = in_sizes[5];           // V * D
    int nb = (Nd + 127) >> 7;

    // ws layout: bcount|bstart|bcursor [MAXB each] | deg[Nd] | pairs[E]
    //            | tmp[Nd*128 f32] | w_bf16[VD ushort] | h[Ns*16 u32]
    int* bcount  = (int*)d_ws;
    int* bstart  = bcount + MAXB;
    int* bcursor = bstart + MAXB;
    int* deg     = bcursor + MAXB;
    unsigned* pairs = (unsigned*)(deg + Nd);
    float* tmp   = (float*)(pairs + E);
    ushort* w_bf16 = (ushort*)(tmp + (size_t)Nd * 128);
    unsigned* h  = (unsigned*)(w_bf16 + VD);

    size_t need_common = (size_t)MAXB * 12 + (size_t)Nd * 4 + (size_t)E * 4
                       + (size_t)Nd * 512;
    size_t need_A = need_common + (size_t)VD * 2;
    size_t need_B = need_A + (size_t)Ns * 64;
    int mode = (ws_size >= need_B) ? 2 : (ws_size >= need_A) ? 1 : 0;

    float* out = (float*)d_out;

    hipLaunchKernelGGL(zero_bcount, dim3(1), dim3(256), 0, stream, bcount, nb);
    hipLaunchKernelGGL(hist_coarse, dim3(512), dim3(256), 0, stream,
                       dst_ids, bcount, E, nb);
    hipLaunchKernelGGL(scan_buckets, dim3(1), dim3(256), 0, stream,
                       bcount, bstart, bcursor, nb);
    hipLaunchKernelGGL(scatter_pairs, dim3((E + 8191) / 8192), dim3(256), 0, stream,
                       src_ids, dst_ids, bcursor, pairs, E, nb);
    if (mode >= 1)
        hipLaunchKernelGGL(cast_w, dim3((VD / 4 + 255) / 256), dim3(256), 0, stream,
                           w, w_bf16, VD);
    if (mode == 2) {
        hipLaunchKernelGGL(build_h, dim3(((size_t)Ns * 16 + 255) / 256), dim3(256),
                           0, stream, Cat_src, w_bf16, h, Ns);
        hipLaunchKernelGGL(agg_from_h, dim3(nb), dim3(256), 0, stream,
                           h, bstart, bcount, pairs, tmp, deg, Nd);
    } else {
        hipLaunchKernelGGL(agg_from_w, dim3(nb), dim3(256), 0, stream,
                           Cat_src, w, w_bf16, mode, bstart, bcount, pairs,
                           tmp, deg, Nd);
    }
    hipLaunchKernelGGL(finalize_dense, dim3((Nd + 255) / 256), dim3(256), 0, stream,
                       Cat_dst, label, w, W_agg, b_agg, w_lin, b_lin,
                       W1, b1, W2, b2, W3, b3, deg, tmp, out, Nd);
}

// Round 6
// 503.686 us; speedup vs baseline: 4.0730x; 1.0233x over previous
//
#include <hip/hip_runtime.h>
#include <math.h>

#define EPSF 1e-5f
#define BSH  6         // log2(bucket size in dst nodes)
#define BSZ  64        // dst nodes per bucket
#define MAXB 2048      // max buckets (Nd/64); Nd=100k -> 1563
#define BCAP 2560      // per-bucket pair capacity (avg 2048, +11 sigma)

__device__ inline unsigned f2bf_rne(float x) {
    unsigned u = __float_as_uint(x);
    u += 0x7FFF + ((u >> 16) & 1);
    return u >> 16;
}
__device__ inline float bf2f_lo(unsigned hv) { return __uint_as_float(hv << 16); }
__device__ inline float bf2f_hi(unsigned hv) { return __uint_as_float(hv & 0xFFFF0000u); }

// ---------------- cast w to bf16 (3.2 MB -> per-XCD L2 resident) -----------
__global__ void cast_w(const float* __restrict__ w, ushort* __restrict__ wb, int n) {
    int i4 = (blockIdx.x * 256 + threadIdx.x) * 4;
    if (i4 + 3 < n) {
        float4 v = *(const float4*)(w + i4);
        ushort4 o;
        o.x = (ushort)f2bf_rne(v.x); o.y = (ushort)f2bf_rne(v.y);
        o.z = (ushort)f2bf_rne(v.z); o.w = (ushort)f2bf_rne(v.w);
        *(ushort4*)(wb + i4) = o;
    } else {
        for (int j = i4; j < n; ++j) wb[j] = (ushort)f2bf_rne(w[j]);
    }
}

// ---------------- precompute h_src: one 64B line per source node -----------
// h[s*16+d] = bf16(mean_f w[cat]) | bf16(max_f w[cat]) << 16
__global__ __launch_bounds__(256) void build_h(
    const int* __restrict__ Cat_src, const ushort* __restrict__ wb,
    unsigned* __restrict__ h, int Ns)
{
    int gid = blockIdx.x * 256 + threadIdx.x;
    int s = gid >> 4;
    if (s >= Ns) return;
    int lane = threadIdx.x & 63;
    int d = lane & 15;
    int c = Cat_src[s * 4 + (d & 3)];
    float vs = 0.f, vm = -INFINITY;
#pragma unroll
    for (int f = 0; f < 4; ++f) {
        int id = __shfl(c, (lane & 48) + f, 64);
        float a = bf2f_lo(wb[id * 16 + d]);
        vs += a; vm = fmaxf(vm, a);
    }
    unsigned packed = f2bf_rne(vs * 0.25f) | (f2bf_rne(vm) << 16);
    __builtin_nontemporal_store(packed, &h[s * 16 + d]);
}

// ---------------- zero bucket counters ----------------
__global__ void zero_bcount(int* bcount, int nb) {
    for (int i = threadIdx.x; i < nb; i += 256) bcount[i] = 0;
}

// ---------------- coarse histogram (LDS-privatized) ----------------
__global__ __launch_bounds__(256) void hist_coarse(const int* __restrict__ dst_ids,
                                                   int* bcount, int E, int nb) {
    __shared__ int h[MAXB];
    for (int i = threadIdx.x; i < nb; i += 256) h[i] = 0;
    __syncthreads();
    int stride = gridDim.x * 256;
    for (int e = blockIdx.x * 256 + threadIdx.x; e < E; e += stride)
        atomicAdd(&h[dst_ids[e] >> BSH], 1);
    __syncthreads();
    for (int i = threadIdx.x; i < nb; i += 256) {
        int c = h[i];
        if (c) atomicAdd(&bcount[i], c);
    }
}

// ---------------- exclusive scan of bucket counts (single block) -----------
__global__ __launch_bounds__(256) void scan_buckets(const int* __restrict__ bcount,
                                                    int* bstart, int* bcursor, int nb) {
    __shared__ int lsum[256];
    int tid = threadIdx.x;
    int v[8];
    int s = 0;
#pragma unroll
    for (int j = 0; j < 8; ++j) {
        int idx = tid * 8 + j;
        v[j] = (idx < nb) ? bcount[idx] : 0;
        s += v[j];
    }
    lsum[tid] = s;
    __syncthreads();
    for (int off = 1; off < 256; off <<= 1) {
        int y = (tid >= off) ? lsum[tid - off] : 0;
        __syncthreads();
        lsum[tid] += y;
        __syncthreads();
    }
    int run = lsum[tid] - s;
#pragma unroll
    for (int j = 0; j < 8; ++j) {
        int idx = tid * 8 + j;
        if (idx < nb) { bstart[idx] = run; bcursor[idx] = run; }
        run += v[j];
    }
}

// ---------------- scatter packed pairs, tile-ranked for run-writes ---------
// pair = (src << 7) | dst_local   (src < 2^20, dl < 64)
__global__ __launch_bounds__(256) void scatter_pairs(
    const int* __restrict__ src_ids, const int* __restrict__ dst_ids,
    int* bcursor, unsigned* __restrict__ pairs, int E, int nb)
{
    __shared__ int cnt[MAXB];
    __shared__ int base[MAXB];
    int tid = threadIdx.x;
    int t0 = blockIdx.x * 8192;
    for (int i = tid; i < nb; i += 256) cnt[i] = 0;
    __syncthreads();
    int rank[32];
#pragma unroll
    for (int j = 0; j < 32; ++j) {
        int e = t0 + j * 256 + tid;
        rank[j] = (e < E) ? atomicAdd(&cnt[dst_ids[e] >> BSH], 1) : 0;
    }
    __syncthreads();
    for (int i = tid; i < nb; i += 256) {
        int c = cnt[i];
        base[i] = c ? atomicAdd(&bcursor[i], c) : 0;
    }
    __syncthreads();
#pragma unroll
    for (int j = 0; j < 32; ++j) {
        int e = t0 + j * 256 + tid;
        if (e < E) {
            int d = dst_ids[e];
            int b = d >> BSH;
            pairs[base[b] + rank[j]] =
                ((unsigned)src_ids[e] << 7) | (unsigned)(d & (BSZ - 1));
        }
    }
}

// ====== per-bucket aggregation: LDS counting sort + register stats =========

__device__ inline void bucket_sort(const unsigned* __restrict__ pairs,
                                   int gbase, int cnt,
                                   unsigned* sp, int* hist, int* ofs, int* start,
                                   int tid)
{
    if (tid < BSZ) hist[tid] = 0;
    __syncthreads();
    for (int i = tid; i < cnt; i += 256)
        atomicAdd(&hist[__builtin_nontemporal_load(&pairs[gbase + i]) & (BSZ - 1)], 1);
    __syncthreads();
    if (tid < BSZ) ofs[tid] = hist[tid];
    __syncthreads();
    for (int off = 1; off < BSZ; off <<= 1) {
        int y = (tid < BSZ && tid >= off) ? ofs[tid - off] : 0;
        __syncthreads();
        if (tid < BSZ) ofs[tid] += y;
        __syncthreads();
    }
    if (tid < BSZ) {
        start[tid] = ofs[tid] - hist[tid];
        ofs[tid] = ofs[tid] - hist[tid];
    }
    __syncthreads();
    for (int i = tid; i < cnt; i += 256) {
        unsigned p = __builtin_nontemporal_load(&pairs[gbase + i]);
        int r = atomicAdd(&ofs[p & (BSZ - 1)], 1);
        sp[r] = p;
    }
    __syncthreads();
}

__device__ inline void emit_stats(float sum0, float sq0, float mn0, float mx0,
                                  float sum1, float sq1, float mn1, float mx1,
                                  int dg, int n, int lane, int sub,
                                  float* __restrict__ tmp, int* __restrict__ deg_out)
{
#pragma unroll
    for (int off = 16; off <= 32; off <<= 1) {
        sum0 += __shfl_xor(sum0, off); sq0 += __shfl_xor(sq0, off);
        mn0 = fminf(mn0, __shfl_xor(mn0, off)); mx0 = fmaxf(mx0, __shfl_xor(mx0, off));
        sum1 += __shfl_xor(sum1, off); sq1 += __shfl_xor(sq1, off);
        mn1 = fminf(mn1, __shfl_xor(mn1, off)); mx1 = fmaxf(mx1, __shfl_xor(mx1, off));
    }
    float safe = fmaxf((float)dg, 1.f);
    float r = 1.f / safe;
    bool has = dg > 0;
    float mean0 = sum0 * r, mean1 = sum1 * r;
    float sd0 = sqrtf(fmaxf(sq0 * r - mean0 * mean0, 0.f) + EPSF);
    float sd1 = sqrtf(fmaxf(sq1 * r - mean1 * mean1, 0.f) + EPSF);
    float v0 = (sub == 0) ? mean0 : (sub == 1) ? (has ? mn0 : 0.f)
             : (sub == 2) ? (has ? mx0 : 0.f) : sd0;
    float v1 = (sub == 0) ? mean1 : (sub == 1) ? (has ? mn1 : 0.f)
             : (sub == 2) ? (has ? mx1 : 0.f) : sd1;
    float* tp = tmp + (size_t)n * 128;
    __builtin_nontemporal_store(v0, &tp[lane]);
    __builtin_nontemporal_store(v1, &tp[64 + lane]);
    if (lane == 0) deg_out[n] = dg;
}

// ---- variant: gather from precomputed packed h (one 64B line per edge) ----
__global__ __launch_bounds__(256) void agg_from_h(
    const unsigned* __restrict__ h,
    const int* __restrict__ bstart, const int* __restrict__ bcount,
    const unsigned* __restrict__ pairs,
    float* __restrict__ tmp, int* __restrict__ deg_out, int Nd)
{
    __shared__ unsigned sp[BCAP];
    __shared__ int hist[BSZ];
    __shared__ int ofs[BSZ];
    __shared__ int start[BSZ];
    int b = blockIdx.x, tid = threadIdx.x;
    int cnt = bcount[b];
    int gbase = bstart[b];
    if (cnt > BCAP) cnt = BCAP;
    bucket_sort(pairs, gbase, cnt, sp, hist, ofs, start, tid);

    int wv = tid >> 6, lane = tid & 63, sub = lane >> 4, d = lane & 15;
#pragma unroll 1
    for (int q = 0; q < 16; ++q) {
        int dl = wv * 16 + q;
        int n = b * BSZ + dl;
        if (n >= Nd) break;
        int st = start[dl], dg = hist[dl];
        float sum0 = 0.f, sq0 = 0.f, mn0 = INFINITY, mx0 = -INFINITY;
        float sum1 = 0.f, sq1 = 0.f, mn1 = INFINITY, mx1 = -INFINITY;
        int nt = (dg + 3) >> 2;
        for (int t = 0; t < nt; ++t) {
            int e4 = t * 4 + sub;
            int ec = (e4 < dg) ? e4 : (dg - 1);
            unsigned p = sp[st + ec];
            unsigned hv = h[(p >> 7) * 16 + d];     // sub's 16 lanes = 1 line
            float me = bf2f_lo(hv);
            float vm = bf2f_hi(hv);
            if (e4 < dg) {
                sum0 += me; sq0 += me * me;
                mn0 = fminf(mn0, me); mx0 = fmaxf(mx0, me);
                sum1 += vm; sq1 += vm * vm;
                mn1 = fminf(mn1, vm); mx1 = fmaxf(mx1, vm);
            }
        }
        emit_stats(sum0, sq0, mn0, mx0, sum1, sq1, mn1, mx1,
                   dg, n, lane, sub, tmp, deg_out);
    }
}

// ---- variant: gather w per edge (bf16 table if use_bf, else fp32) ---------
__global__ __launch_bounds__(256) void agg_from_w(
    const int* __restrict__ Cat_src, const float* __restrict__ w,
    const ushort* __restrict__ wb, int use_bf,
    const int* __restrict__ bstart, const int* __restrict__ bcount,
    const unsigned* __restrict__ pairs,
    float* __restrict__ tmp, int* __restrict__ deg_out, int Nd)
{
    __shared__ unsigned sp[BCAP];
    __shared__ int hist[BSZ];
    __shared__ int ofs[BSZ];
    __shared__ int start[BSZ];
    int b = blockIdx.x, tid = threadIdx.x;
    int cnt = bcount[b];
    int gbase = bstart[b];
    if (cnt > BCAP) cnt = BCAP;
    bucket_sort(pairs, gbase, cnt, sp, hist, ofs, start, tid);

    int wv = tid >> 6, lane = tid & 63, sub = lane >> 4, d = lane & 15;
#pragma unroll 1
    for (int q = 0; q < 16; ++q) {
        int dl = wv * 16 + q;
        int n = b * BSZ + dl;
        if (n >= Nd) break;
        int st = start[dl], dg = hist[dl];
        float sum0 = 0.f, sq0 = 0.f, mn0 = INFINITY, mx0 = -INFINITY;
        float sum1 = 0.f, sq1 = 0.f, mn1 = INFINITY, mx1 = -INFINITY;
        int nt = (dg + 3) >> 2;
        for (int t = 0; t < nt; ++t) {
            int e4 = t * 4 + sub;
            int ec = (e4 < dg) ? e4 : (dg - 1);
            unsigned p = sp[st + ec];
            int src = (int)(p >> 7);
            int cat = Cat_src[src * 4 + (d & 3)];
            float vs = 0.f, vm = -INFINITY;
            if (use_bf) {
#pragma unroll
                for (int f = 0; f < 4; ++f) {
                    int id = __shfl(cat, sub * 16 + f, 64);
                    float a = bf2f_lo(wb[id * 16 + d]);
                    vs += a; vm = fmaxf(vm, a);
                }
            } else {
#pragma unroll
                for (int f = 0; f < 4; ++f) {
                    int id = __shfl(cat, sub * 16 + f, 64);
                    float a = w[id * 16 + d];
                    vs += a; vm = fmaxf(vm, a);
                }
            }
            if (e4 < dg) {
                float me = vs * 0.25f;
                sum0 += me; sq0 += me * me;
                mn0 = fminf(mn0, me); mx0 = fmaxf(mx0, me);
                sum1 += vm; sq1 += vm * vm;
                mn1 = fminf(mn1, vm); mx1 = fmaxf(mx1, vm);
            }
        }
        emit_stats(sum0, sq0, mn0, mx0, sum1, sq1, mn1, mx1,
                   dg, n, lane, sub, tmp, deg_out);
    }
}

// ---------------- finalize: ONE NODE per lane, weights via scalar loads ----
__global__ __launch_bounds__(256) void finalize_dense(
    const int* __restrict__ Cat_dst, const int* __restrict__ label,
    const float* __restrict__ w,
    const float* __restrict__ W_agg, const float* __restrict__ b_agg,
    const float* __restrict__ w_lin, const float* __restrict__ b_lin,
    const float* __restrict__ W1, const float* __restrict__ b1,
    const float* __restrict__ W2, const float* __restrict__ b2,
    const float* __restrict__ W3, const float* __restrict__ b3,
    const int* __restrict__ deg_arr, const float* __restrict__ tmp,
    float* __restrict__ out, int Nd)
{
    int n = blockIdx.x * 256 + threadIdx.x;
    if (n >= Nd) return;
    float fdeg = (float)deg_arr[n];
    float logd = logf(fdeg + 1.f);
    const float logavg = logf(33.0f);          // log(AVG_D + 1)
    float amp = logd / logavg;
    float att = (logd > 0.f) ? (logavg / fmaxf(logd, EPSF)) : 0.f;

    float mes[32];
    const float4* T4 = (const float4*)(tmp + (size_t)n * 128);
#pragma unroll
    for (int k = 0; k < 2; ++k) {
        float accA[16], accB[16], accC[16];
#pragma unroll
        for (int d = 0; d < 16; ++d) { accA[d] = 0.f; accB[d] = 0.f; accC[d] = 0.f; }
        const float* Wk = W_agg + k * 3072;
        for (int c = 0; c < 16; ++c) {
            float4 t = T4[k * 16 + c];
#pragma unroll
            for (int u = 0; u < 4; ++u) {
                float tv = (u == 0) ? t.x : (u == 1) ? t.y : (u == 2) ? t.z : t.w;
                const float* w0 = Wk + (c * 4 + u) * 16;
#pragma unroll
                for (int d = 0; d < 16; ++d) {
                    accA[d] += tv * w0[d];
                    accB[d] += tv * w0[1024 + d];
                    accC[d] += tv * w0[2048 + d];
                }
            }
        }
#pragma unroll
        for (int d = 0; d < 16; ++d)
            mes[k * 16 + d] = b_agg[k * 16 + d] + accA[d] + amp * accB[d] + att * accC[d];
    }

    float lin = 0.f, sq = 0.f;
    float sd[16];
#pragma unroll
    for (int u = 0; u < 16; ++u) sd[u] = 0.f;
    float acc1[64];
#pragma unroll
    for (int j = 0; j < 64; ++j) acc1[j] = b1[j];

    for (int c = 0; c < 4; ++c) {
        int cid = Cat_dst[n * 4 + c];
        const float4* R = (const float4*)(w + (size_t)cid * 16);
        float4 r0 = R[0], r1 = R[1], r2 = R[2], r3 = R[3];
        float xi[16] = { r0.x, r0.y, r0.z, r0.w, r1.x, r1.y, r1.z, r1.w,
                         r2.x, r2.y, r2.z, r2.w, r3.x, r3.y, r3.z, r3.w };
#pragma unroll
        for (int u = 0; u < 16; ++u) {
            float v = xi[u];
            int i = c * 16 + u;
            lin += v * w_lin[i];
            sd[u] += v;
            sq += v * v;
#pragma unroll
            for (int j = 0; j < 64; ++j) acc1[j] += v * W1[i * 64 + j];
        }
    }
#pragma unroll
    for (int k = 0; k < 2; ++k) {
#pragma unroll
        for (int u = 0; u < 16; ++u) {
            float v = mes[k * 16 + u];
            int i = 64 + k * 16 + u;
            lin += v * w_lin[i];
            sd[u] += v;
            sq += v * v;
#pragma unroll
            for (int j = 0; j < 64; ++j) acc1[j] += v * W1[i * 64 + j];
        }
    }
    float fm = 0.f;
#pragma unroll
    for (int u = 0; u < 16; ++u) fm += sd[u] * sd[u];
    fm = 0.5f * (fm - sq);

    float acc2[32];
#pragma unroll
    for (int j = 0; j < 32; ++j) acc2[j] = b2[j];
#pragma unroll
    for (int i = 0; i < 64; ++i) {
        float h = fmaxf(acc1[i], 0.f);
#pragma unroll
        for (int j = 0; j < 32; ++j) acc2[j] += h * W2[i * 32 + j];
    }
    float deep = b3[0];
#pragma unroll
    for (int j = 0; j < 32; ++j) deep += fmaxf(acc2[j], 0.f) * W3[j];

    float z = lin + b_lin[0] + fm + deep;
    float pred = 1.f / (1.f + expf(-z));
    out[n] = pred;
    out[Nd + n] = (float)label[n];
}

extern "C" void kernel_launch(void* const* d_in, const int* in_sizes, int n_in,
                              void* d_out, int out_size, void* d_ws, size_t ws_size,
                              hipStream_t stream) {
    const int*   Cat_src = (const int*)d_in[0];
    const int*   Cat_dst = (const int*)d_in[1];
    const int*   src_ids = (const int*)d_in[2];
    const int*   dst_ids = (const int*)d_in[3];
    const int*   label   = (const int*)d_in[4];
    const float* w       = (const float*)d_in[5];
    const float* W_agg   = (const float*)d_in[6];
    const float* b_agg   = (const float*)d_in[7];
    const float* w_lin   = (const float*)d_in[8];
    const float* b_lin   = (const float*)d_in[9];
    const float* W1      = (const float*)d_in[10];
    const float* b1      = (const float*)d_in[11];
    const float* W2      = (const float*)d_in[12];
    const float* b2      = (const float*)d_in[13];
    const float* W3      = (const float*)d_in[14];
    const float* b3      = (const float*)d_in[15];

    int E  = in_sizes[2];
    int Nd = in_sizes[4];
    int Ns = in_sizes[0] / 4;       // Cat_src is Ns x 4
    int VD = in_sizes[5];           // V * D
    int nb = (Nd + BSZ - 1) >> BSH;

    // ws layout: bcount|bstart|bcursor [MAXB each] | deg[Nd] | pairs[E]
    //            | tmp[Nd*128 f32] | w_bf16[VD ushort] | h[Ns*16 u32]
    int* bcount  = (int*)d_ws;
    int* bstart  = bcount + MAXB;
    int* bcursor = bstart + MAXB;
    int* deg     = bcursor + MAXB;
    unsigned* pairs = (unsigned*)(deg + Nd);
    float* tmp   = (float*)(pairs + E);
    ushort* w_bf16 = (ushort*)(tmp + (size_t)Nd * 128);
    unsigned* h  = (unsigned*)(w_bf16 + VD);

    size_t need_common = (size_t)MAXB * 12 + (size_t)Nd * 4 + (size_t)E * 4
                       + (size_t)Nd * 512;
    size_t need_A = need_common + (size_t)VD * 2;
    size_t need_B = need_A + (size_t)Ns * 64;
    int mode = (ws_size >= need_B) ? 2 : (ws_size >= need_A) ? 1 : 0;

    float* out = (float*)d_out;

    hipLaunchKernelGGL(zero_bcount, dim3(1), dim3(256), 0, stream, bcount, nb);
    hipLaunchKernelGGL(hist_coarse, dim3(512), dim3(256), 0, stream,
                       dst_ids, bcount, E, nb);
    hipLaunchKernelGGL(scan_buckets, dim3(1), dim3(256), 0, stream,
                       bcount, bstart, bcursor, nb);
    hipLaunchKernelGGL(scatter_pairs, dim3((E + 8191) / 8192), dim3(256), 0, stream,
                       src_ids, dst_ids, bcursor, pairs, E, nb);
    if (mode >= 1)
        hipLaunchKernelGGL(cast_w, dim3((VD / 4 + 255) / 256), dim3(256), 0, stream,
                           w, w_bf16, VD);
    if (mode == 2) {
        hipLaunchKernelGGL(build_h, dim3(((size_t)Ns * 16 + 255) / 256), dim3(256),
                           0, stream, Cat_src, w_bf16, h, Ns);
        hipLaunchKernelGGL(agg_from_h, dim3(nb), dim3(256), 0, stream,
                           h, bstart, bcount, pairs, tmp, deg, Nd);
    } else {
        hipLaunchKernelGGL(agg_from_w, dim3(nb), dim3(256), 0, stream,
                           Cat_src, w, w_bf16, mode, bstart, bcount, pairs,
                           tmp, deg, Nd);
    }
    hipLaunchKernelGGL(finalize_dense, dim3((Nd + 255) / 256), dim3(256), 0, stream,
                       Cat_dst, label, w, W_agg, b_agg, w_lin, b_lin,
                       W1, b1, W2, b2, W3, b3, deg, tmp, out, Nd);
}

// Round 7
// 390.668 us; speedup vs baseline: 5.2513x; 1.2893x over previous
//
#include <hip/hip_runtime.h>
#include <math.h>

#define EPSF 1e-5f
#define BSH  6         // log2(bucket size in dst nodes)
#define BSZ  64        // dst nodes per bucket
#define MAXB 2048      // max buckets (Nd/64); Nd=100k -> 1563
#define BCAP 2560      // per-bucket pair capacity (avg 2048, +11 sigma)
#define XPAD 100       // x row stride (f32 words), mult of 4 for b128 align
#define X2PAD 68

typedef __attribute__((ext_vector_type(8))) short short8;
typedef __attribute__((ext_vector_type(4))) float float4v;

__device__ inline unsigned f2bf_rne(float x) {
    unsigned u = __float_as_uint(x);
    u += 0x7FFF + ((u >> 16) & 1);
    return u >> 16;
}
__device__ inline short bf16_of(float x) { return (short)f2bf_rne(x); }
__device__ inline float bf2f_lo(unsigned hv) { return __uint_as_float(hv << 16); }
__device__ inline float bf2f_hi(unsigned hv) { return __uint_as_float(hv & 0xFFFF0000u); }

// ---------------- cast w to bf16 (3.2 MB -> per-XCD L2 resident) -----------
__global__ void cast_w(const float* __restrict__ w, ushort* __restrict__ wb, int n) {
    int i4 = (blockIdx.x * 256 + threadIdx.x) * 4;
    if (i4 + 3 < n) {
        float4 v = *(const float4*)(w + i4);
        ushort4 o;
        o.x = (ushort)f2bf_rne(v.x); o.y = (ushort)f2bf_rne(v.y);
        o.z = (ushort)f2bf_rne(v.z); o.w = (ushort)f2bf_rne(v.w);
        *(ushort4*)(wb + i4) = o;
    } else {
        for (int j = i4; j < n; ++j) wb[j] = (ushort)f2bf_rne(w[j]);
    }
}

// ---------------- precompute h_src: one 64B line per source node -----------
__global__ __launch_bounds__(256) void build_h(
    const int* __restrict__ Cat_src, const ushort* __restrict__ wb,
    unsigned* __restrict__ h, int Ns)
{
    int gid = blockIdx.x * 256 + threadIdx.x;
    int s = gid >> 4;
    if (s >= Ns) return;
    int lane = threadIdx.x & 63;
    int d = lane & 15;
    int c = Cat_src[s * 4 + (d & 3)];
    float vs = 0.f, vm = -INFINITY;
#pragma unroll
    for (int f = 0; f < 4; ++f) {
        int id = __shfl(c, (lane & 48) + f, 64);
        float a = bf2f_lo(wb[id * 16 + d]);
        vs += a; vm = fmaxf(vm, a);
    }
    unsigned packed = f2bf_rne(vs * 0.25f) | (f2bf_rne(vm) << 16);
    __builtin_nontemporal_store(packed, &h[s * 16 + d]);
}

// ---------------- zero bucket counters ----------------
__global__ void zero_bcount(int* bcount, int nb) {
    for (int i = threadIdx.x; i < nb; i += 256) bcount[i] = 0;
}

// ---------------- coarse histogram (LDS-privatized) ----------------
__global__ __launch_bounds__(256) void hist_coarse(const int* __restrict__ dst_ids,
                                                   int* bcount, int E, int nb) {
    __shared__ int h[MAXB];
    for (int i = threadIdx.x; i < nb; i += 256) h[i] = 0;
    __syncthreads();
    int stride = gridDim.x * 256;
    for (int e = blockIdx.x * 256 + threadIdx.x; e < E; e += stride)
        atomicAdd(&h[dst_ids[e] >> BSH], 1);
    __syncthreads();
    for (int i = threadIdx.x; i < nb; i += 256) {
        int c = h[i];
        if (c) atomicAdd(&bcount[i], c);
    }
}

// ---------------- exclusive scan of bucket counts (single block) -----------
__global__ __launch_bounds__(256) void scan_buckets(const int* __restrict__ bcount,
                                                    int* bstart, int* bcursor, int nb) {
    __shared__ int lsum[256];
    int tid = threadIdx.x;
    int v[8];
    int s = 0;
#pragma unroll
    for (int j = 0; j < 8; ++j) {
        int idx = tid * 8 + j;
        v[j] = (idx < nb) ? bcount[idx] : 0;
        s += v[j];
    }
    lsum[tid] = s;
    __syncthreads();
    for (int off = 1; off < 256; off <<= 1) {
        int y = (tid >= off) ? lsum[tid - off] : 0;
        __syncthreads();
        lsum[tid] += y;
        __syncthreads();
    }
    int run = lsum[tid] - s;
#pragma unroll
    for (int j = 0; j < 8; ++j) {
        int idx = tid * 8 + j;
        if (idx < nb) { bstart[idx] = run; bcursor[idx] = run; }
        run += v[j];
    }
}

// ---------------- scatter packed pairs, tile-ranked for run-writes ---------
__global__ __launch_bounds__(256) void scatter_pairs(
    const int* __restrict__ src_ids, const int* __restrict__ dst_ids,
    int* bcursor, unsigned* __restrict__ pairs, int E, int nb)
{
    __shared__ int cnt[MAXB];
    __shared__ int base[MAXB];
    int tid = threadIdx.x;
    int t0 = blockIdx.x * 8192;
    for (int i = tid; i < nb; i += 256) cnt[i] = 0;
    __syncthreads();
    int rank[32];
#pragma unroll
    for (int j = 0; j < 32; ++j) {
        int e = t0 + j * 256 + tid;
        rank[j] = (e < E) ? atomicAdd(&cnt[dst_ids[e] >> BSH], 1) : 0;
    }
    __syncthreads();
    for (int i = tid; i < nb; i += 256) {
        int c = cnt[i];
        base[i] = c ? atomicAdd(&bcursor[i], c) : 0;
    }
    __syncthreads();
#pragma unroll
    for (int j = 0; j < 32; ++j) {
        int e = t0 + j * 256 + tid;
        if (e < E) {
            int d = dst_ids[e];
            int b = d >> BSH;
            pairs[base[b] + rank[j]] =
                ((unsigned)src_ids[e] << 7) | (unsigned)(d & (BSZ - 1));
        }
    }
}

// ====== per-bucket aggregation: LDS counting sort + register stats =========

__device__ inline void bucket_sort(const unsigned* __restrict__ pairs,
                                   int gbase, int cnt,
                                   unsigned* sp, int* hist, int* ofs, int* start,
                                   int tid)
{
    if (tid < BSZ) hist[tid] = 0;
    __syncthreads();
    for (int i = tid; i < cnt; i += 256)
        atomicAdd(&hist[__builtin_nontemporal_load(&pairs[gbase + i]) & (BSZ - 1)], 1);
    __syncthreads();
    if (tid < BSZ) ofs[tid] = hist[tid];
    __syncthreads();
    for (int off = 1; off < BSZ; off <<= 1) {
        int y = (tid < BSZ && tid >= off) ? ofs[tid - off] : 0;
        __syncthreads();
        if (tid < BSZ) ofs[tid] += y;
        __syncthreads();
    }
    if (tid < BSZ) {
        start[tid] = ofs[tid] - hist[tid];
        ofs[tid] = ofs[tid] - hist[tid];
    }
    __syncthreads();
    for (int i = tid; i < cnt; i += 256) {
        unsigned p = __builtin_nontemporal_load(&pairs[gbase + i]);
        int r = atomicAdd(&ofs[p & (BSZ - 1)], 1);
        sp[r] = p;
    }
    __syncthreads();
}

__device__ inline void emit_stats(float sum0, float sq0, float mn0, float mx0,
                                  float sum1, float sq1, float mn1, float mx1,
                                  int dg, int n, int lane, int sub,
                                  float* __restrict__ tmp, int* __restrict__ deg_out)
{
#pragma unroll
    for (int off = 16; off <= 32; off <<= 1) {
        sum0 += __shfl_xor(sum0, off); sq0 += __shfl_xor(sq0, off);
        mn0 = fminf(mn0, __shfl_xor(mn0, off)); mx0 = fmaxf(mx0, __shfl_xor(mx0, off));
        sum1 += __shfl_xor(sum1, off); sq1 += __shfl_xor(sq1, off);
        mn1 = fminf(mn1, __shfl_xor(mn1, off)); mx1 = fmaxf(mx1, __shfl_xor(mx1, off));
    }
    float safe = fmaxf((float)dg, 1.f);
    float r = 1.f / safe;
    bool has = dg > 0;
    float mean0 = sum0 * r, mean1 = sum1 * r;
    float sd0 = sqrtf(fmaxf(sq0 * r - mean0 * mean0, 0.f) + EPSF);
    float sd1 = sqrtf(fmaxf(sq1 * r - mean1 * mean1, 0.f) + EPSF);
    float v0 = (sub == 0) ? mean0 : (sub == 1) ? (has ? mn0 : 0.f)
             : (sub == 2) ? (has ? mx0 : 0.f) : sd0;
    float v1 = (sub == 0) ? mean1 : (sub == 1) ? (has ? mn1 : 0.f)
             : (sub == 2) ? (has ? mx1 : 0.f) : sd1;
    float* tp = tmp + (size_t)n * 128;
    __builtin_nontemporal_store(v0, &tp[lane]);
    __builtin_nontemporal_store(v1, &tp[64 + lane]);
    if (lane == 0) deg_out[n] = dg;
}

// ---- gather from precomputed packed h (one 64B line per edge) ----
__global__ __launch_bounds__(256) void agg_from_h(
    const unsigned* __restrict__ h,
    const int* __restrict__ bstart, const int* __restrict__ bcount,
    const unsigned* __restrict__ pairs,
    float* __restrict__ tmp, int* __restrict__ deg_out, int Nd)
{
    __shared__ unsigned sp[BCAP];
    __shared__ int hist[BSZ];
    __shared__ int ofs[BSZ];
    __shared__ int start[BSZ];
    int b = blockIdx.x, tid = threadIdx.x;
    int cnt = bcount[b];
    int gbase = bstart[b];
    if (cnt > BCAP) cnt = BCAP;
    bucket_sort(pairs, gbase, cnt, sp, hist, ofs, start, tid);

    int wv = tid >> 6, lane = tid & 63, sub = lane >> 4, d = lane & 15;
#pragma unroll 1
    for (int q = 0; q < 16; ++q) {
        int dl = wv * 16 + q;
        int n = b * BSZ + dl;
        if (n >= Nd) break;
        int st = start[dl], dg = hist[dl];
        float sum0 = 0.f, sq0 = 0.f, mn0 = INFINITY, mx0 = -INFINITY;
        float sum1 = 0.f, sq1 = 0.f, mn1 = INFINITY, mx1 = -INFINITY;
        int nt = (dg + 3) >> 2;
        for (int t = 0; t < nt; ++t) {
            int e4 = t * 4 + sub;
            int ec = (e4 < dg) ? e4 : (dg - 1);
            unsigned p = sp[st + ec];
            unsigned hv = h[(p >> 7) * 16 + d];
            float me = bf2f_lo(hv);
            float vm = bf2f_hi(hv);
            if (e4 < dg) {
                sum0 += me; sq0 += me * me;
                mn0 = fminf(mn0, me); mx0 = fmaxf(mx0, me);
                sum1 += vm; sq1 += vm * vm;
                mn1 = fminf(mn1, vm); mx1 = fmaxf(mx1, vm);
            }
        }
        emit_stats(sum0, sq0, mn0, mx0, sum1, sq1, mn1, mx1,
                   dg, n, lane, sub, tmp, deg_out);
    }
}

// ---- fallback: gather w per edge (bf16 table if use_bf, else fp32) --------
__global__ __launch_bounds__(256) void agg_from_w(
    const int* __restrict__ Cat_src, const float* __restrict__ w,
    const ushort* __restrict__ wb, int use_bf,
    const int* __restrict__ bstart, const int* __restrict__ bcount,
    const unsigned* __restrict__ pairs,
    float* __restrict__ tmp, int* __restrict__ deg_out, int Nd)
{
    __shared__ unsigned sp[BCAP];
    __shared__ int hist[BSZ];
    __shared__ int ofs[BSZ];
    __shared__ int start[BSZ];
    int b = blockIdx.x, tid = threadIdx.x;
    int cnt = bcount[b];
    int gbase = bstart[b];
    if (cnt > BCAP) cnt = BCAP;
    bucket_sort(pairs, gbase, cnt, sp, hist, ofs, start, tid);

    int wv = tid >> 6, lane = tid & 63, sub = lane >> 4, d = lane & 15;
#pragma unroll 1
    for (int q = 0; q < 16; ++q) {
        int dl = wv * 16 + q;
        int n = b * BSZ + dl;
        if (n >= Nd) break;
        int st = start[dl], dg = hist[dl];
        float sum0 = 0.f, sq0 = 0.f, mn0 = INFINITY, mx0 = -INFINITY;
        float sum1 = 0.f, sq1 = 0.f, mn1 = INFINITY, mx1 = -INFINITY;
        int nt = (dg + 3) >> 2;
        for (int t = 0; t < nt; ++t) {
            int e4 = t * 4 + sub;
            int ec = (e4 < dg) ? e4 : (dg - 1);
            unsigned p = sp[st + ec];
            int src = (int)(p >> 7);
            int cat = Cat_src[src * 4 + (d & 3)];
            float vs = 0.f, vm = -INFINITY;
            if (use_bf) {
#pragma unroll
                for (int f = 0; f < 4; ++f) {
                    int id = __shfl(cat, sub * 16 + f, 64);
                    float a = bf2f_lo(wb[id * 16 + d]);
                    vs += a; vm = fmaxf(vm, a);
                }
            } else {
#pragma unroll
                for (int f = 0; f < 4; ++f) {
                    int id = __shfl(cat, sub * 16 + f, 64);
                    float a = w[id * 16 + d];
                    vs += a; vm = fmaxf(vm, a);
                }
            }
            if (e4 < dg) {
                float me = vs * 0.25f;
                sum0 += me; sq0 += me * me;
                mn0 = fminf(mn0, me); mx0 = fmaxf(mx0, me);
                sum1 += vm; sq1 += vm * vm;
                mn1 = fminf(mn1, vm); mx1 = fmaxf(mx1, vm);
            }
        }
        emit_stats(sum0, sq0, mn0, mx0, sum1, sq1, mn1, mx1,
                   dg, n, lane, sub, tmp, deg_out);
    }
}

// ---------------- finalize via MFMA: 16 nodes per wave, 64 per block -------
// Layouts (gfx950, verified): A[m=lane&15][k=(lane>>4)*8+j];
// B[k=(lane>>4)*8+j][n=lane&15]; C/D col=lane&15, row=(lane>>4)*4+reg.
__global__ __launch_bounds__(256) void finalize_mfma(
    const int* __restrict__ Cat_dst, const int* __restrict__ label,
    const float* __restrict__ w,
    const float* __restrict__ W_agg, const float* __restrict__ b_agg,
    const float* __restrict__ w_lin, const float* __restrict__ b_lin,
    const float* __restrict__ W1, const float* __restrict__ b1,
    const float* __restrict__ W2, const float* __restrict__ b2,
    const float* __restrict__ W3, const float* __restrict__ b3,
    const int* __restrict__ deg_arr, const float* __restrict__ tmp,
    float* __restrict__ out, int Nd)
{
    __shared__ __align__(16) float sx[4][16 * XPAD];   // per-wave x [16][96]
    __shared__ __align__(16) float sx2[4][16 * X2PAD]; // per-wave h1 [16][64]
    __shared__ float sdeep[4][16];

    int tid = threadIdx.x;
    int wv = tid >> 6, lane = tid & 63;
    int q = lane >> 4, m = lane & 15;
    int n0 = (blockIdx.x * 4 + wv) * 16;
    int n = n0 + m;
    int nc = (n < Nd) ? n : (Nd - 1);

    float* X = sx[wv];
    float* X2 = sx2[wv];

    // ---- PNA scalers for node m
    float fdeg = (float)deg_arr[nc];
    float logd = logf(fdeg + 1.f);
    const float logavg = logf(33.0f);
    float amp = logd / logavg;
    float att = (logd > 0.f) ? (logavg / fmaxf(logd, EPSF)) : 0.f;

    // ---- Phase A: mes = scaled @ W_agg + b_agg  (2x GEMM 16x192x16)
    const float* tpn = tmp + (size_t)nc * 128;
#pragma unroll
    for (int kvar = 0; kvar < 2; ++kvar) {
        float4v acc = {0.f, 0.f, 0.f, 0.f};
#pragma unroll
        for (int t = 0; t < 6; ++t) {
            int blk = t >> 1;
            float s = (blk == 0) ? 1.f : (blk == 1) ? amp : att;
            const float* ap = tpn + kvar * 64 + (t & 1) * 32 + q * 8;
            float4 a0 = *(const float4*)ap;
            float4 a1 = *(const float4*)(ap + 4);
            short8 af;
            af[0] = bf16_of(a0.x * s); af[1] = bf16_of(a0.y * s);
            af[2] = bf16_of(a0.z * s); af[3] = bf16_of(a0.w * s);
            af[4] = bf16_of(a1.x * s); af[5] = bf16_of(a1.y * s);
            af[6] = bf16_of(a1.z * s); af[7] = bf16_of(a1.w * s);
            const float* bp = W_agg + kvar * 3072 + (t * 32 + q * 8) * 16 + m;
            short8 bf;
#pragma unroll
            for (int j = 0; j < 8; ++j) bf[j] = bf16_of(bp[j * 16]);
            acc = __builtin_amdgcn_mfma_f32_16x16x32_bf16(af, bf, acc, 0, 0, 0);
        }
        float bias = b_agg[kvar * 16 + m];
#pragma unroll
        for (int r = 0; r < 4; ++r)
            X[(q * 4 + r) * XPAD + 64 + kvar * 16 + m] = acc[r] + bias;
    }

    // ---- Phase B: dst cat embeddings -> X cols 0..63 (one (node,field)/lane)
    {
        int nl = lane >> 2, fl = lane & 3;
        int nn = n0 + nl;
        int nnc = (nn < Nd) ? nn : (Nd - 1);
        int cid = Cat_dst[nnc * 4 + fl];
        const float4* R = (const float4*)(w + (size_t)cid * 16);
        float* xp = X + nl * XPAD + fl * 16;
        *(float4*)(xp + 0)  = R[0];
        *(float4*)(xp + 4)  = R[1];
        *(float4*)(xp + 8)  = R[2];
        *(float4*)(xp + 12) = R[3];
    }
    __syncthreads();

    // ---- Phase D: lin / FM stats for node m (q splits the 6 fields)
    float lin = 0.f, sq = 0.f;
    float sd[16];
#pragma unroll
    for (int u = 0; u < 16; ++u) sd[u] = 0.f;
    {
        const float* xp = X + m * XPAD + q * 16;
        const float* wl = w_lin + q * 16;
#pragma unroll
        for (int u = 0; u < 16; ++u) {
            float v = xp[u];
            lin += v * wl[u]; sq += v * v; sd[u] += v;
        }
    }
    if (q < 2) {
        const float* xp = X + m * XPAD + (4 + q) * 16;
        const float* wl = w_lin + (4 + q) * 16;
#pragma unroll
        for (int u = 0; u < 16; ++u) {
            float v = xp[u];
            lin += v * wl[u]; sq += v * v; sd[u] += v;
        }
    }
#pragma unroll
    for (int off = 16; off <= 32; off <<= 1) {
        lin += __shfl_xor(lin, off);
        sq  += __shfl_xor(sq, off);
#pragma unroll
        for (int u = 0; u < 16; ++u) sd[u] += __shfl_xor(sd[u], off);
    }
    float fm = 0.f;
#pragma unroll
    for (int u = 0; u < 16; ++u) fm += sd[u] * sd[u];
    fm = 0.5f * (fm - sq);

    // ---- Phase E: h1 = relu(x @ W1 + b1)   (GEMM 16x96x64)
    short8 xa[3];
#pragma unroll
    for (int t = 0; t < 3; ++t) {
        const float* xp = X + m * XPAD + t * 32 + q * 8;
        float4 a0 = *(const float4*)xp;
        float4 a1 = *(const float4*)(xp + 4);
        xa[t][0] = bf16_of(a0.x); xa[t][1] = bf16_of(a0.y);
        xa[t][2] = bf16_of(a0.z); xa[t][3] = bf16_of(a0.w);
        xa[t][4] = bf16_of(a1.x); xa[t][5] = bf16_of(a1.y);
        xa[t][6] = bf16_of(a1.z); xa[t][7] = bf16_of(a1.w);
    }
#pragma unroll
    for (int nt = 0; nt < 4; ++nt) {
        float4v acc = {0.f, 0.f, 0.f, 0.f};
#pragma unroll
        for (int t = 0; t < 3; ++t) {
            const float* bp = W1 + (t * 32 + q * 8) * 64 + nt * 16 + m;
            short8 bf;
#pragma unroll
            for (int j = 0; j < 8; ++j) bf[j] = bf16_of(bp[j * 64]);
            acc = __builtin_amdgcn_mfma_f32_16x16x32_bf16(xa[t], bf, acc, 0, 0, 0);
        }
        float bb = b1[nt * 16 + m];
#pragma unroll
        for (int r = 0; r < 4; ++r)
            X2[(q * 4 + r) * X2PAD + nt * 16 + m] = fmaxf(acc[r] + bb, 0.f);
    }
    __syncthreads();

    // ---- Phase F: h2 = relu(h1 @ W2 + b2); deep = h2 @ W3
    short8 ha[2];
#pragma unroll
    for (int t = 0; t < 2; ++t) {
        const float* xp = X2 + m * X2PAD + t * 32 + q * 8;
        float4 a0 = *(const float4*)xp;
        float4 a1 = *(const float4*)(xp + 4);
        ha[t][0] = bf16_of(a0.x); ha[t][1] = bf16_of(a0.y);
        ha[t][2] = bf16_of(a0.z); ha[t][3] = bf16_of(a0.w);
        ha[t][4] = bf16_of(a1.x); ha[t][5] = bf16_of(a1.y);
        ha[t][6] = bf16_of(a1.z); ha[t][7] = bf16_of(a1.w);
    }
    float dp[4] = {0.f, 0.f, 0.f, 0.f};
#pragma unroll
    for (int nt = 0; nt < 2; ++nt) {
        float4v acc = {0.f, 0.f, 0.f, 0.f};
#pragma unroll
        for (int t = 0; t < 2; ++t) {
            const float* bp = W2 + (t * 32 + q * 8) * 32 + nt * 16 + m;
            short8 bf;
#pragma unroll
            for (int j = 0; j < 8; ++j) bf[j] = bf16_of(bp[j * 32]);
            acc = __builtin_amdgcn_mfma_f32_16x16x32_bf16(ha[t], bf, acc, 0, 0, 0);
        }
        float bb = b2[nt * 16 + m];
        float w3 = W3[nt * 16 + m];
#pragma unroll
        for (int r = 0; r < 4; ++r)
            dp[r] += fmaxf(acc[r] + bb, 0.f) * w3;
    }
#pragma unroll
    for (int off = 1; off <= 8; off <<= 1) {
#pragma unroll
        for (int r = 0; r < 4; ++r) dp[r] += __shfl_xor(dp[r], off);
    }
    if (m < 4)
        sdeep[wv][q * 4 + m] = (m == 0) ? dp[0] : (m == 1) ? dp[1]
                             : (m == 2) ? dp[2] : dp[3];
    __syncthreads();
    float deep = sdeep[wv][m];

    if (q == 0 && n < Nd) {
        float z = lin + b_lin[0] + fm + deep + b3[0];
        float pred = 1.f / (1.f + expf(-z));
        out[n] = pred;
        out[Nd + n] = (float)label[n];
    }
}

extern "C" void kernel_launch(void* const* d_in, const int* in_sizes, int n_in,
                              void* d_out, int out_size, void* d_ws, size_t ws_size,
                              hipStream_t stream) {
    const int*   Cat_src = (const int*)d_in[0];
    const int*   Cat_dst = (const int*)d_in[1];
    const int*   src_ids = (const int*)d_in[2];
    const int*   dst_ids = (const int*)d_in[3];
    const int*   label   = (const int*)d_in[4];
    const float* w       = (const float*)d_in[5];
    const float* W_agg   = (const float*)d_in[6];
    const float* b_agg   = (const float*)d_in[7];
    const float* w_lin   = (const float*)d_in[8];
    const float* b_lin   = (const float*)d_in[9];
    const float* W1      = (const float*)d_in[10];
    const float* b1      = (const float*)d_in[11];
    const float* W2      = (const float*)d_in[12];
    const float* b2      = (const float*)d_in[13];
    const float* W3      = (const float*)d_in[14];
    const float* b3      = (const float*)d_in[15];

    int E  = in_sizes[2];
    int Nd = in_sizes[4];
    int Ns = in_sizes[0] / 4;
    int VD = in_sizes[5];
    int nb = (Nd + BSZ - 1) >> BSH;

    int* bcount  = (int*)d_ws;
    int* bstart  = bcount + MAXB;
    int* bcursor = bstart + MAXB;
    int* deg     = bcursor + MAXB;
    unsigned* pairs = (unsigned*)(deg + Nd);
    float* tmp   = (float*)(pairs + E);
    ushort* w_bf16 = (ushort*)(tmp + (size_t)Nd * 128);
    unsigned* h  = (unsigned*)(w_bf16 + VD);

    size_t need_common = (size_t)MAXB * 12 + (size_t)Nd * 4 + (size_t)E * 4
                       + (size_t)Nd * 512;
    size_t need_A = need_common + (size_t)VD * 2;
    size_t need_B = need_A + (size_t)Ns * 64;
    int mode = (ws_size >= need_B) ? 2 : (ws_size >= need_A) ? 1 : 0;

    float* out = (float*)d_out;

    hipLaunchKernelGGL(zero_bcount, dim3(1), dim3(256), 0, stream, bcount, nb);
    hipLaunchKernelGGL(hist_coarse, dim3(512), dim3(256), 0, stream,
                       dst_ids, bcount, E, nb);
    hipLaunchKernelGGL(scan_buckets, dim3(1), dim3(256), 0, stream,
                       bcount, bstart, bcursor, nb);
    hipLaunchKernelGGL(scatter_pairs, dim3((E + 8191) / 8192), dim3(256), 0, stream,
                       src_ids, dst_ids, bcursor, pairs, E, nb);
    if (mode >= 1)
        hipLaunchKernelGGL(cast_w, dim3((VD / 4 + 255) / 256), dim3(256), 0, stream,
                           w, w_bf16, VD);
    if (mode == 2) {
        hipLaunchKernelGGL(build_h, dim3(((size_t)Ns * 16 + 255) / 256), dim3(256),
                           0, stream, Cat_src, w_bf16, h, Ns);
        hipLaunchKernelGGL(agg_from_h, dim3(nb), dim3(256), 0, stream,
                           h, bstart, bcount, pairs, tmp, deg, Nd);
    } else {
        hipLaunchKernelGGL(agg_from_w, dim3(nb), dim3(256), 0, stream,
                           Cat_src, w, w_bf16, mode, bstart, bcount, pairs,
                           tmp, deg, Nd);
    }
    hipLaunchKernelGGL(finalize_mfma, dim3((Nd + 63) / 64), dim3(256), 0, stream,
                       Cat_dst, label, w, W_agg, b_agg, w_lin, b_lin,
                       W1, b1, W2, b2, W3, b3, deg, tmp, out, Nd);
}